// Round 14
// baseline (161.309 us; speedup 1.0000x reference)
//
#include <hip/hip_runtime.h>

#define NFULL 4096
#define CDIM  512
#define HEADS 8
#define DDIM  64

typedef unsigned short u16;
typedef short bf16x8 __attribute__((ext_vector_type(8)));
typedef float f32x4 __attribute__((ext_vector_type(4)));

#if __has_builtin(__builtin_amdgcn_exp2f)
__device__ __forceinline__ float exp2_hw(float x) { return __builtin_amdgcn_exp2f(x); }
#else
__device__ __forceinline__ float exp2_hw(float x) {
  float r;
  asm volatile("v_exp_f32 %0, %1\n\ts_nop 1" : "=v"(r) : "v"(x));
  return r;
}
#endif
#define EXP2(x) exp2_hw(x)

// q pre-scaled by SCALE * log2(e) so exp(s) == exp2(s').
#define QSCALE 11.541560327111707f  // 8 * 1.4426950408889634

__device__ __forceinline__ float dot4(float4 a, float4 b) {
  return a.x * b.x + a.y * b.y + a.z * b.z + a.w * b.w;
}

__device__ __forceinline__ u16 f2bf(float x) {  // RNE f32 -> bf16 bits
  union { float f; unsigned u; } v; v.f = x;
  unsigned r = v.u + 0x7fffu + ((v.u >> 16) & 1u);
  return (u16)(r >> 16);
}

__device__ __forceinline__ float bf2f(u16 b) {
  union { unsigned u; float f; } v; v.u = ((unsigned)b) << 16;
  return v.f;
}

// K1: blocks 0..127: t_bf[32 rows][96] = bf16(x @ [q_w1;kv_w1]^T), MFMA,
// coalesced stores via swapped operands (D[w-col][x-row]).
// Blocks 128..129: bias2. 130..193: pwbf. 194..197: pw1bf. 198..201: pw2bf.
__global__ __launch_bounds__(256) void k_pre(const float* __restrict__ x,
                                             const float* __restrict__ qw1,
                                             const float* __restrict__ kvw1,
                                             u16* __restrict__ t_bf,
                                             const float* __restrict__ pww,
                                             const float* __restrict__ dww,
                                             const float* __restrict__ dwb,
                                             const float* __restrict__ pwb,
                                             const float* __restrict__ pw1,
                                             const float* __restrict__ pw2,
                                             float* __restrict__ bias2,
                                             u16* __restrict__ pwbf,
                                             u16* __restrict__ pw1bf,
                                             u16* __restrict__ pw2bf) {
  __shared__ __align__(16) u16 Xs[32][72];
  __shared__ __align__(16) u16 Ws[96][72];
  const int tid = threadIdx.x;

  if (blockIdx.x >= 128) {  // weight prep
    const int b = blockIdx.x - 128;
    if (b < 2) {
      const int c = b * 256 + tid;
      float acc = 0.f;
      for (int e = 0; e < 512; e += 4)
        acc += dot4(*(const float4*)&pww[(size_t)c * 512 + e], *(const float4*)&dwb[e]);
      bias2[c] = acc + pwb[c];
    } else {
      const float* src;
      u16* dst;
      bool scale = false;
      int base;
      if (b < 66)      { base = (b - 2) * 4096 + tid * 16;  src = pww; dst = pwbf; scale = true; }
      else if (b < 70) { base = (b - 66) * 4096 + tid * 16; src = pw1; dst = pw1bf; }
      else             { base = (b - 70) * 4096 + tid * 16; src = pw2; dst = pw2bf; }
      const int e0 = base & 511;
      u16 o[16];
#pragma unroll
      for (int q = 0; q < 4; ++q) {
        float4 w = *(const float4*)&src[base + q * 4];
        if (scale) {
          const float4 d = *(const float4*)&dww[e0 + q * 4];
          w.x *= d.x; w.y *= d.y; w.z *= d.z; w.w *= d.w;
        }
        o[q * 4 + 0] = f2bf(w.x); o[q * 4 + 1] = f2bf(w.y);
        o[q * 4 + 2] = f2bf(w.z); o[q * 4 + 3] = f2bf(w.w);
      }
      *(uint4*)&dst[base] = *(const uint4*)&o[0];
      *(uint4*)&dst[base + 8] = *(const uint4*)&o[8];
    }
    return;
  }

  const int r0 = blockIdx.x * 32;
  const int wave = tid >> 6, lane = tid & 63;
  const int lrow = lane & 15, g = lane >> 4;
  const int rs = wave >> 1, ws2 = wave & 1;

  f32x4 acc[3];
#pragma unroll
  for (int sub = 0; sub < 3; ++sub) acc[sub] = (f32x4){0.f, 0.f, 0.f, 0.f};

  for (int k0 = 0; k0 < 512; k0 += 64) {
    __syncthreads();
    {
      const int row = tid >> 3, c16 = (tid & 7) * 8;
      const float* __restrict__ src = x + (size_t)(r0 + row) * 512 + k0 + c16;
      const float4 v0 = *(const float4*)(src);
      const float4 v1 = *(const float4*)(src + 4);
      u16 tmp[8] = {f2bf(v0.x), f2bf(v0.y), f2bf(v0.z), f2bf(v0.w),
                    f2bf(v1.x), f2bf(v1.y), f2bf(v1.z), f2bf(v1.w)};
      *(uint4*)&Xs[row][c16] = *(const uint4*)&tmp[0];
    }
    for (int u = tid; u < 768; u += 256) {
      const int c = u >> 3, c16 = (u & 7) * 8;
      const float* __restrict__ src =
          (c < 32 ? qw1 + (size_t)c * 512 : kvw1 + (size_t)(c - 32) * 512) + k0 + c16;
      const float4 v0 = *(const float4*)(src);
      const float4 v1 = *(const float4*)(src + 4);
      u16 tmp[8] = {f2bf(v0.x), f2bf(v0.y), f2bf(v0.z), f2bf(v0.w),
                    f2bf(v1.x), f2bf(v1.y), f2bf(v1.z), f2bf(v1.w)};
      *(uint4*)&Ws[c][c16] = *(const uint4*)&tmp[0];
    }
    __syncthreads();
    const bf16x8 a0 = *(const bf16x8*)&Xs[rs * 16 + lrow][g * 8];
    const bf16x8 a1 = *(const bf16x8*)&Xs[rs * 16 + lrow][32 + g * 8];
#pragma unroll
    for (int sub = 0; sub < 3; ++sub) {
      const int c = (ws2 * 3 + sub) * 16 + lrow;
      const bf16x8 b0 = *(const bf16x8*)&Ws[c][g * 8];
      const bf16x8 b1 = *(const bf16x8*)&Ws[c][32 + g * 8];
      acc[sub] = __builtin_amdgcn_mfma_f32_16x16x32_bf16(b0, a0, acc[sub], 0, 0, 0);
      acc[sub] = __builtin_amdgcn_mfma_f32_16x16x32_bf16(b1, a1, acc[sub], 0, 0, 0);
    }
  }
  // D[w-col g*4+j][x-row lrow]: 4 consecutive cols per lane -> uint2 stores
  const int n = r0 + rs * 16 + lrow;
#pragma unroll
  for (int sub = 0; sub < 3; ++sub) {
    u16 o4[4] = {f2bf(acc[sub][0]), f2bf(acc[sub][1]),
                 f2bf(acc[sub][2]), f2bf(acc[sub][3])};
    *(uint2*)&t_bf[(size_t)n * 96 + (ws2 * 3 + sub) * 16 + g * 4] = *(const uint2*)o4;
  }
}

// K2: q/k/v projections, MFMA with swapped operands -> coalesced stores.
// Grid 768 = 64 row x 12 col blocks.
__global__ __launch_bounds__(256) void k_proj2(const u16* __restrict__ t_bf,
                                               const float* __restrict__ qw2,
                                               const float* __restrict__ kvw2,
                                               u16* __restrict__ qb,
                                               u16* __restrict__ kb,
                                               float* __restrict__ vh) {
  __shared__ __align__(16) u16 Ts[64][72];
  __shared__ __align__(16) u16 Wsh[128][72];
  const int cb = blockIdx.x % 12;
  const int r0 = (blockIdx.x / 12) * 64;
  const int tid = threadIdx.x;
  const int wave = tid >> 6, lane = tid & 63;
  const int lrow = lane & 15, g = lane >> 4;
  const bool isq = cb < 4;
  const int c0 = isq ? cb * 128 : 512 + (cb - 4) * 128;

  for (int u = tid; u < 512; u += 256) {
    const int row = u >> 3, ch = (u & 7) * 8;
    uint4 v = {0u, 0u, 0u, 0u};
    if (isq) {
      if (ch < 32) v = *(const uint4*)&t_bf[(size_t)(r0 + row) * 96 + ch];
    } else {
      v = *(const uint4*)&t_bf[(size_t)(r0 + row) * 96 + 32 + ch];
    }
    *(uint4*)&Ts[row][ch] = v;
  }
  if (isq) {
    for (int u = tid; u < 1024; u += 256) {
      const int col = u >> 3, cf = (u & 7) * 4;
      const float4 v = *(const float4*)&qw2[(size_t)(c0 + col) * 32 + cf];
      u16 tmp[4] = {f2bf(v.x), f2bf(v.y), f2bf(v.z), f2bf(v.w)};
      *(uint2*)&Wsh[col][cf] = *(const uint2*)&tmp[0];
    }
  } else {
    for (int u = tid; u < 2048; u += 256) {
      const int col = u >> 4, cf = (u & 15) * 4;
      const float4 v = *(const float4*)&kvw2[(size_t)(c0 - 512 + col) * 64 + cf];
      u16 tmp[4] = {f2bf(v.x), f2bf(v.y), f2bf(v.z), f2bf(v.w)};
      *(uint2*)&Wsh[col][cf] = *(const uint2*)&tmp[0];
    }
  }
  __syncthreads();

  const int n = r0 + wave * 16 + lrow;  // this lane's output row
  if (isq) {
    const bf16x8 aq = *(const bf16x8*)&Ts[wave * 16 + lrow][g * 8];
#pragma unroll
    for (int sub = 0; sub < 8; ++sub) {
      const bf16x8 b0 = *(const bf16x8*)&Wsh[sub * 16 + lrow][g * 8];
      f32x4 acc = {0.f, 0.f, 0.f, 0.f};
      acc = __builtin_amdgcn_mfma_f32_16x16x32_bf16(b0, aq, acc, 0, 0, 0);
      // D[w-col g*4+j][t-row lrow]: 4 consecutive output cols
      const int colg0 = c0 + sub * 16 + g * 4;
      const int hh = colg0 >> 6, d0 = colg0 & 63;
      u16 o4[4] = {f2bf(acc[0] * QSCALE), f2bf(acc[1] * QSCALE),
                   f2bf(acc[2] * QSCALE), f2bf(acc[3] * QSCALE)};
      *(uint2*)&qb[((size_t)hh * NFULL + n) * 64 + d0] = *(const uint2*)o4;
    }
  } else {
    const bf16x8 a0 = *(const bf16x8*)&Ts[wave * 16 + lrow][g * 8];
    const bf16x8 a1 = *(const bf16x8*)&Ts[wave * 16 + lrow][32 + g * 8];
#pragma unroll
    for (int sub = 0; sub < 8; ++sub) {
      const bf16x8 b0 = *(const bf16x8*)&Wsh[sub * 16 + lrow][g * 8];
      const bf16x8 b1 = *(const bf16x8*)&Wsh[sub * 16 + lrow][32 + g * 8];
      f32x4 acc = {0.f, 0.f, 0.f, 0.f};
      acc = __builtin_amdgcn_mfma_f32_16x16x32_bf16(b0, a0, acc, 0, 0, 0);
      acc = __builtin_amdgcn_mfma_f32_16x16x32_bf16(b1, a1, acc, 0, 0, 0);
      const int colg0 = c0 + sub * 16 + g * 4;  // 512..1532
      if (colg0 < 1024) {
        const int c2 = colg0 - 512;
        const int hh = c2 >> 6, d0 = c2 & 63;
        u16 o4[4] = {f2bf(acc[0]), f2bf(acc[1]), f2bf(acc[2]), f2bf(acc[3])};
        *(uint2*)&kb[((size_t)hh * NFULL + n) * 64 + d0] = *(const uint2*)o4;
      } else {
        const int c2 = colg0 - 1024;
        const int hh = c2 >> 6, d0 = c2 & 63;
        float4 o4;
        o4.x = acc[0]; o4.y = acc[1]; o4.z = acc[2]; o4.w = acc[3];
        *(float4*)&vh[((size_t)hh * NFULL + n) * 64 + d0] = o4;
      }
    }
  }
}

// K3: attention. Block (h, qt, s): 64 queries, keys [s*1024,+1024) in 16 tiles.
// Wave-private global_load_lds staging, 4-deep circular swizzled LDS buffer,
// counted vmcnt, no main-loop barriers, no setprio (4 waves/SIMD contend).
__global__ __launch_bounds__(256, 4) void k_attn(const u16* __restrict__ qb,
                                                 const u16* __restrict__ kb,
                                                 const float* __restrict__ vh,
                                                 u16* __restrict__ wv16,
                                                 float* __restrict__ dsp) {
  __shared__ __align__(16) u16 KB[4][64][64];  // 32 KB, rows XOR-swizzled
  __shared__ float P_lds[4][16][17];
  __shared__ float Ds[4][4][16];

  const int h = blockIdx.x & 7;            // XCD affinity
  const int qt = (blockIdx.x >> 3) & 63;
  const int s = blockIdx.x >> 9;           // 0..3
  const int q0 = qt * 64;
  const int tid = threadIdx.x;
  const int wave = tid >> 6, lane = tid & 63;
  const int lrow = lane & 15, g = lane >> 4;

  const u16* __restrict__ Qg = qb + ((size_t)h * NFULL + q0) * 64;
  const u16* __restrict__ Kg = kb + ((size_t)h * NFULL + (size_t)s * 1024) * 64;

  bf16x8 qf[4][2];
#pragma unroll
  for (int f = 0; f < 4; ++f) {
    qf[f][0] = *(const bf16x8*)&Qg[(f * 16 + lrow) * 64 + g * 8];
    qf[f][1] = *(const bf16x8*)&Qg[(f * 16 + lrow) * 64 + 32 + g * 8];
  }

  const int srow8 = lane >> 3;
  const int scol = ((lane & 7) ^ srow8) << 3;

#define STAGE(T, B)                                                           \
  do {                                                                        \
    const u16* tb_ = Kg + (size_t)(T) * 64 * 64;                              \
    {                                                                         \
      const u16* src_ = tb_ + (wave * 16 + srow8) * 64 + scol;                \
      u16* dst_ = &KB[(B)][wave * 16][0];                                     \
      __builtin_amdgcn_global_load_lds(                                       \
          (const __attribute__((address_space(1))) unsigned*)src_,            \
          (__attribute__((address_space(3))) unsigned*)dst_, 16, 0, 0);       \
    }                                                                         \
    {                                                                         \
      const u16* src_ = tb_ + (wave * 16 + 8 + srow8) * 64 + scol;            \
      u16* dst_ = &KB[(B)][wave * 16][0] + 512;                               \
      __builtin_amdgcn_global_load_lds(                                       \
          (const __attribute__((address_space(1))) unsigned*)src_,            \
          (__attribute__((address_space(3))) unsigned*)dst_, 16, 0, 0);       \
    }                                                                         \
  } while (0)

  const int rsw = wave * 16 + lrow;
  const int x0 = (g ^ (lrow & 7)) * 8;
  const int x1 = ((g + 4) ^ (lrow & 7)) * 8;

  float dsum[4] = {0.f, 0.f, 0.f, 0.f};
  const bool dg = (s == (qt >> 4));
  const int tdiag = qt & 15;

  auto tile = [&](int t, int b) {
    const bf16x8 kf0 = *(const bf16x8*)&KB[b][rsw][x0];
    const bf16x8 kf1 = *(const bf16x8*)&KB[b][rsw][x1];
    f32x4 a[4];
#pragma unroll
    for (int f = 0; f < 4; ++f) {
      f32x4 t4 = {0.f, 0.f, 0.f, 0.f};
      t4 = __builtin_amdgcn_mfma_f32_16x16x32_bf16(kf0, qf[f][0], t4, 0, 0, 0);
      t4 = __builtin_amdgcn_mfma_f32_16x16x32_bf16(kf1, qf[f][1], t4, 0, 0, 0);
      a[f] = t4;
    }
    const bool isd = dg && (t == tdiag);
#pragma unroll
    for (int f = 0; f < 4; ++f) {
      const float e0 = EXP2(a[f][0]);
      const float e1 = EXP2(a[f][1]);
      const float e2 = EXP2(a[f][2]);
      const float e3 = EXP2(a[f][3]);
      dsum[f] += (e0 + e1) + (e2 + e3);
      if (isd && f == wave) {
        const int rr = g * 4;
        P_lds[wave][rr + 0][lrow] = (rr + 0 <= lrow) ? e0 : 0.f;
        P_lds[wave][rr + 1][lrow] = (rr + 1 <= lrow) ? e1 : 0.f;
        P_lds[wave][rr + 2][lrow] = (rr + 2 <= lrow) ? e2 : 0.f;
        P_lds[wave][rr + 3][lrow] = (rr + 3 <= lrow) ? e3 : 0.f;
      }
    }
  };

  STAGE(0, 0); STAGE(1, 1); STAGE(2, 2);

  for (int t = 0; t < 13; ++t) {
    STAGE(t + 3, (t + 3) & 3);
    asm volatile("s_waitcnt vmcnt(6)" ::: "memory");
    tile(t, t & 3);
  }
  asm volatile("s_waitcnt vmcnt(4)" ::: "memory");
  tile(13, 1);
  asm volatile("s_waitcnt vmcnt(2)" ::: "memory");
  tile(14, 2);
  asm volatile("s_waitcnt vmcnt(0)" ::: "memory");
  tile(15, 3);
#undef STAGE

#pragma unroll
  for (int f = 0; f < 4; ++f) {
    dsum[f] += __shfl_xor(dsum[f], 16);
    dsum[f] += __shfl_xor(dsum[f], 32);
  }
  if (g == 0) {
#pragma unroll
    for (int f = 0; f < 4; ++f) Ds[wave][f][lrow] = dsum[f];
  }
  __syncthreads();

  if (tid < 64) {
    const int f = tid >> 4, r = tid & 15;
    const float den = Ds[0][f][r] + Ds[1][f][r] + Ds[2][f][r] + Ds[3][f][r];
    dsp[((size_t)s * HEADS + h) * NFULL + q0 + f * 16 + r] = den;
  }

  if (dg) {
    const float* __restrict__ V =
        vh + ((size_t)h * NFULL + q0 + wave * 16) * 64 + g * 16;
    float o[16];
#pragma unroll
    for (int dd = 0; dd < 16; ++dd) o[dd] = 0.f;
#pragma unroll
    for (int k = 0; k < 16; ++k) {
      const float p = P_lds[wave][k][lrow];
      const float4 v0 = *(const float4*)&V[k * 64 + 0];
      const float4 v1 = *(const float4*)&V[k * 64 + 4];
      const float4 v2 = *(const float4*)&V[k * 64 + 8];
      const float4 v3 = *(const float4*)&V[k * 64 + 12];
      o[0] += p * v0.x;  o[1] += p * v0.y;  o[2] += p * v0.z;  o[3] += p * v0.w;
      o[4] += p * v1.x;  o[5] += p * v1.y;  o[6] += p * v1.z;  o[7] += p * v1.w;
      o[8] += p * v2.x;  o[9] += p * v2.y;  o[10] += p * v2.z; o[11] += p * v2.w;
      o[12] += p * v3.x; o[13] += p * v3.y; o[14] += p * v3.z; o[15] += p * v3.w;
    }
    u16 ob[16];
#pragma unroll
    for (int dd = 0; dd < 16; ++dd) ob[dd] = f2bf(o[dd]);
    u16* __restrict__ op =
        wv16 + (size_t)(q0 + wave * 16 + lrow) * CDIM + h * 64 + g * 16;
    *(uint4*)&op[0] = *(const uint4*)&ob[0];
    *(uint4*)&op[8] = *(const uint4*)&ob[8];
  }
}

// K4: y16 = bf16(normalize(wv16) @ pwbf^T + bias2 + x); denom = 4 dsp splits.
__global__ __launch_bounds__(256) void k_dyn(const u16* __restrict__ wv16,
                                             const float* __restrict__ x,
                                             const u16* __restrict__ pwbf,
                                             const float* __restrict__ bias2,
                                             const float* __restrict__ dsp,
                                             u16* __restrict__ y16) {
  __shared__ __align__(16) u16 Ab[64][72];
  __shared__ __align__(16) u16 Wb[64][72];
  const int rb = blockIdx.x >> 3, cb = blockIdx.x & 7;
  const int r0 = rb * 64, c0 = cb * 64;
  const int tid = threadIdx.x;
  const int wave = tid >> 6, lane = tid & 63;
  const int lrow = lane & 15, g = lane >> 4;
  const int srow = tid >> 2;
  const int skc = (tid & 3) * 16;

  float inv8[8];
#pragma unroll
  for (int hh = 0; hh < 8; ++hh) {
    const size_t base = (size_t)hh * NFULL + r0 + srow;
    inv8[hh] = 1.0f / (dsp[base] + dsp[(size_t)8 * NFULL + base] +
                       dsp[(size_t)16 * NFULL + base] + dsp[(size_t)24 * NFULL + base]);
  }

  f32x4 acc[4];
#pragma unroll
  for (int ct = 0; ct < 4; ++ct) acc[ct] = (f32x4){0.f, 0.f, 0.f, 0.f};

  const u16* __restrict__ ap = wv16 + (size_t)(r0 + srow) * 512 + skc;
  const u16* __restrict__ wp = pwbf + (size_t)(c0 + srow) * 512 + skc;
  uint4 av0 = *(const uint4*)ap;
  uint4 av1 = *(const uint4*)(ap + 8);
  uint4 w0 = *(const uint4*)wp;
  uint4 w1 = *(const uint4*)(wp + 8);

  for (int k0 = 0; k0 < 512; k0 += 64) {
    const float sc = inv8[k0 >> 6];
    u16 ab16[16];
    const u16* pa0 = (const u16*)&av0;
    const u16* pa1 = (const u16*)&av1;
#pragma unroll
    for (int e = 0; e < 8; ++e) ab16[e] = f2bf(bf2f(pa0[e]) * sc);
#pragma unroll
    for (int e = 0; e < 8; ++e) ab16[8 + e] = f2bf(bf2f(pa1[e]) * sc);
    __syncthreads();
    *(uint4*)&Ab[srow][skc] = *(const uint4*)&ab16[0];
    *(uint4*)&Ab[srow][skc + 8] = *(const uint4*)&ab16[8];
    *(uint4*)&Wb[srow][skc] = w0;
    *(uint4*)&Wb[srow][skc + 8] = w1;
    __syncthreads();
    if (k0 + 64 < 512) {
      av0 = *(const uint4*)(ap + k0 + 64);
      av1 = *(const uint4*)(ap + k0 + 64 + 8);
      w0 = *(const uint4*)(wp + k0 + 64);
      w1 = *(const uint4*)(wp + k0 + 64 + 8);
    }
#pragma unroll
    for (int kk = 0; kk < 2; ++kk) {
      const bf16x8 af = *(const bf16x8*)&Ab[wave * 16 + lrow][kk * 32 + g * 8];
#pragma unroll
      for (int ct = 0; ct < 4; ++ct) {
        const bf16x8 wf = *(const bf16x8*)&Wb[ct * 16 + lrow][kk * 32 + g * 8];
        acc[ct] = __builtin_amdgcn_mfma_f32_16x16x32_bf16(wf, af, acc[ct], 0, 0, 0);
      }
    }
  }
  const int row = r0 + wave * 16 + lrow;
#pragma unroll
  for (int ct = 0; ct < 4; ++ct) {
    const int c = c0 + ct * 16 + g * 4;
    const float4 bb = *(const float4*)&bias2[c];
    const float4 xv = *(const float4*)&x[(size_t)row * 512 + c];
    u16 o4[4];
    o4[0] = f2bf(acc[ct][0] + bb.x + xv.x);
    o4[1] = f2bf(acc[ct][1] + bb.y + xv.y);
    o4[2] = f2bf(acc[ct][2] + bb.z + xv.z);
    o4[3] = f2bf(acc[ct][3] + bb.w + xv.w);
    *(uint2*)&y16[(size_t)row * 512 + c] = *(const uint2*)o4;
  }
}

// K5: out = ((y @ p_w1^T) @ p_w2^T) fused via MFMA. Grid 512 = 256 row-tiles
// x 2 col-halves (phase1 duplicated per half; raises occupancy 2x).
__global__ __launch_bounds__(256) void k_pout(const u16* __restrict__ y16,
                                              const u16* __restrict__ pw1bf,
                                              const u16* __restrict__ pw2bf,
                                              float* __restrict__ out) {
  __shared__ __align__(16) u16 yb[16][520];
  __shared__ float tp_part[2][32][17];
  const int r0 = (blockIdx.x >> 1) * 16;
  const int chalf = blockIdx.x & 1;
  const int tid = threadIdx.x;
  const int wave = tid >> 6, lane = tid & 63;
  const int lrow = lane & 15, g = lane >> 4;

  for (int rep = 0; rep < 4; ++rep) {
    const int idx = rep * 256 + tid;
    const int row = idx >> 6, c8 = (idx & 63) * 8;
    *(uint4*)&yb[row][c8] = *(const uint4*)&y16[(size_t)(r0 + row) * 512 + c8];
  }
  __syncthreads();

  {
    const int ct1 = wave & 1, kh = wave >> 1;
    f32x4 acc = {0.f, 0.f, 0.f, 0.f};
#pragma unroll
    for (int ks = 0; ks < 8; ++ks) {
      const int K = kh * 256 + ks * 32 + g * 8;
      const bf16x8 aw = *(const bf16x8*)&pw1bf[(size_t)(ct1 * 16 + lrow) * 512 + K];
      const bf16x8 bf = *(const bf16x8*)&yb[lrow][K];
      acc = __builtin_amdgcn_mfma_f32_16x16x32_bf16(aw, bf, acc, 0, 0, 0);
    }
#pragma unroll
    for (int j = 0; j < 4; ++j)
      tp_part[kh][ct1 * 16 + g * 4 + j][lrow] = acc[j];
  }
  __syncthreads();

  union { u16 a[8]; bf16x8 v; } bq;
#pragma unroll
  for (int i = 0; i < 8; ++i) {
    const int k = g * 8 + i;
    bq.a[i] = f2bf(tp_part[0][k][lrow] + tp_part[1][k][lrow]);
  }

#pragma unroll
  for (int t = 0; t < 4; ++t) {
    const int ct = chalf * 16 + wave * 4 + t;
    const bf16x8 aw = *(const bf16x8*)&pw2bf[(size_t)(ct * 16 + lrow) * 32 + g * 8];
    f32x4 acc = {0.f, 0.f, 0.f, 0.f};
    acc = __builtin_amdgcn_mfma_f32_16x16x32_bf16(aw, bq.v, acc, 0, 0, 0);
    float4 res;
    res.x = acc[0]; res.y = acc[1]; res.z = acc[2]; res.w = acc[3];
    *(float4*)&out[(size_t)(r0 + lrow) * 512 + ct * 16 + g * 4] = res;
  }
}

extern "C" void kernel_launch(void* const* d_in, const int* in_sizes, int n_in,
                              void* d_out, int out_size, void* d_ws, size_t ws_size,
                              hipStream_t stream) {
  const float* x     = (const float*)d_in[0];
  const float* q_w1  = (const float*)d_in[1];
  const float* q_w2  = (const float*)d_in[2];
  const float* kv_w1 = (const float*)d_in[3];
  const float* kv_w2 = (const float*)d_in[4];
  const float* dw_w  = (const float*)d_in[5];
  const float* dw_b  = (const float*)d_in[6];
  const float* pw_w  = (const float*)d_in[7];
  const float* pw_b  = (const float*)d_in[8];
  const float* p_w1  = (const float*)d_in[9];
  const float* p_w2  = (const float*)d_in[10];
  float* out = (float*)d_out;

  char* ws = (char*)d_ws;
  float* dsp   = (float*)ws;                      // 4*8*4096 f32 (512KB)
  float* bias2 = (float*)(ws + 524288);           // 1024 f32 (4KB)
  u16*   pwbf  = (u16*)(ws + 524288 + 4096);      // 512*512 u16 (512KB)
  u16*   pw1bf = pwbf + 262144;                   // 16384 u16 (32KB)
  u16*   pw2bf = pw1bf + 16384;                   // 16384 u16 (32KB)
  u16*   t_bf  = pw2bf + 16384;                   // 4096*96 u16 (768KB)
  u16*   qbw   = t_bf + (size_t)NFULL * 96;       // 2M u16 (4MB)
  u16*   kbw   = qbw + (size_t)HEADS * NFULL * DDIM;  // 2M u16 (4MB)
  float* vh    = (float*)(kbw + (size_t)HEADS * NFULL * DDIM);  // 2M f32 (8MB)
  u16*   wv16  = (u16*)(vh + (size_t)HEADS * NFULL * DDIM);     // 2M u16 (4MB)
  u16*   y16   = qbw;  // alias (qb dead after k_attn)

  k_pre<<<202, 256, 0, stream>>>(x, q_w1, kv_w1, t_bf, pw_w, dw_w, dw_b, pw_b,
                                 p_w1, p_w2, bias2, pwbf, pw1bf, pw2bf);
  k_proj2<<<(NFULL / 64) * 12, 256, 0, stream>>>(t_bf, q_w2, kv_w2, qbw, kbw, vh);
  k_attn<<<4 * HEADS * (NFULL / 64), 256, 0, stream>>>(qbw, kbw, vh, wv16, dsp);
  k_dyn<<<(NFULL / 64) * 8, 256, 0, stream>>>(wv16, x, pwbf, bias2, dsp, y16);
  k_pout<<<(NFULL / 16) * 2, 256, 0, stream>>>(y16, pw1bf, pw2bf, out);
}

// Round 15
// 84.572 us; speedup vs baseline: 1.9074x; 1.9074x over previous
//
#include <hip/hip_runtime.h>

#define NFULL 4096
#define CDIM  512
#define HEADS 8
#define DDIM  64

typedef unsigned short u16;
typedef short bf16x8 __attribute__((ext_vector_type(8)));
typedef float f32x4 __attribute__((ext_vector_type(4)));

#if __has_builtin(__builtin_amdgcn_exp2f)
__device__ __forceinline__ float exp2_hw(float x) { return __builtin_amdgcn_exp2f(x); }
#else
__device__ __forceinline__ float exp2_hw(float x) {
  float r;
  asm volatile("v_exp_f32 %0, %1\n\ts_nop 1" : "=v"(r) : "v"(x));
  return r;
}
#endif
#define EXP2(x) exp2_hw(x)

// q pre-scaled by SCALE * log2(e) so exp(s) == exp2(s').
#define QSCALE 11.541560327111707f  // 8 * 1.4426950408889634

__device__ __forceinline__ float dot4(float4 a, float4 b) {
  return a.x * b.x + a.y * b.y + a.z * b.z + a.w * b.w;
}

__device__ __forceinline__ u16 f2bf(float x) {  // RNE f32 -> bf16 bits
  union { float f; unsigned u; } v; v.f = x;
  unsigned r = v.u + 0x7fffu + ((v.u >> 16) & 1u);
  return (u16)(r >> 16);
}

__device__ __forceinline__ float bf2f(u16 b) {
  union { unsigned u; float f; } v; v.u = ((unsigned)b) << 16;
  return v.f;
}

// K1: blocks 0..127: t_bf[32 rows][96] = bf16(x @ [q_w1;kv_w1]^T), MFMA,
// coalesced stores via swapped operands. 128..129: bias2. 130..193: pwbf.
// 194..197: pw1bf. 198..201: pw2bf.
__global__ __launch_bounds__(256) void k_pre(const float* __restrict__ x,
                                             const float* __restrict__ qw1,
                                             const float* __restrict__ kvw1,
                                             u16* __restrict__ t_bf,
                                             const float* __restrict__ pww,
                                             const float* __restrict__ dww,
                                             const float* __restrict__ dwb,
                                             const float* __restrict__ pwb,
                                             const float* __restrict__ pw1,
                                             const float* __restrict__ pw2,
                                             float* __restrict__ bias2,
                                             u16* __restrict__ pwbf,
                                             u16* __restrict__ pw1bf,
                                             u16* __restrict__ pw2bf) {
  __shared__ __align__(16) u16 Xs[32][72];
  __shared__ __align__(16) u16 Ws[96][72];
  const int tid = threadIdx.x;

  if (blockIdx.x >= 128) {  // weight prep
    const int b = blockIdx.x - 128;
    if (b < 2) {
      const int c = b * 256 + tid;
      float acc = 0.f;
      for (int e = 0; e < 512; e += 4)
        acc += dot4(*(const float4*)&pww[(size_t)c * 512 + e], *(const float4*)&dwb[e]);
      bias2[c] = acc + pwb[c];
    } else {
      const float* src;
      u16* dst;
      bool scale = false;
      int base;
      if (b < 66)      { base = (b - 2) * 4096 + tid * 16;  src = pww; dst = pwbf; scale = true; }
      else if (b < 70) { base = (b - 66) * 4096 + tid * 16; src = pw1; dst = pw1bf; }
      else             { base = (b - 70) * 4096 + tid * 16; src = pw2; dst = pw2bf; }
      const int e0 = base & 511;
      u16 o[16];
#pragma unroll
      for (int q = 0; q < 4; ++q) {
        float4 w = *(const float4*)&src[base + q * 4];
        if (scale) {
          const float4 d = *(const float4*)&dww[e0 + q * 4];
          w.x *= d.x; w.y *= d.y; w.z *= d.z; w.w *= d.w;
        }
        o[q * 4 + 0] = f2bf(w.x); o[q * 4 + 1] = f2bf(w.y);
        o[q * 4 + 2] = f2bf(w.z); o[q * 4 + 3] = f2bf(w.w);
      }
      *(uint4*)&dst[base] = *(const uint4*)&o[0];
      *(uint4*)&dst[base + 8] = *(const uint4*)&o[8];
    }
    return;
  }

  const int r0 = blockIdx.x * 32;
  const int wave = tid >> 6, lane = tid & 63;
  const int lrow = lane & 15, g = lane >> 4;
  const int rs = wave >> 1, ws2 = wave & 1;

  f32x4 acc[3];
#pragma unroll
  for (int sub = 0; sub < 3; ++sub) acc[sub] = (f32x4){0.f, 0.f, 0.f, 0.f};

  for (int k0 = 0; k0 < 512; k0 += 64) {
    __syncthreads();
    {
      const int row = tid >> 3, c16 = (tid & 7) * 8;
      const float* __restrict__ src = x + (size_t)(r0 + row) * 512 + k0 + c16;
      const float4 v0 = *(const float4*)(src);
      const float4 v1 = *(const float4*)(src + 4);
      u16 tmp[8] = {f2bf(v0.x), f2bf(v0.y), f2bf(v0.z), f2bf(v0.w),
                    f2bf(v1.x), f2bf(v1.y), f2bf(v1.z), f2bf(v1.w)};
      *(uint4*)&Xs[row][c16] = *(const uint4*)&tmp[0];
    }
    for (int u = tid; u < 768; u += 256) {
      const int c = u >> 3, c16 = (u & 7) * 8;
      const float* __restrict__ src =
          (c < 32 ? qw1 + (size_t)c * 512 : kvw1 + (size_t)(c - 32) * 512) + k0 + c16;
      const float4 v0 = *(const float4*)(src);
      const float4 v1 = *(const float4*)(src + 4);
      u16 tmp[8] = {f2bf(v0.x), f2bf(v0.y), f2bf(v0.z), f2bf(v0.w),
                    f2bf(v1.x), f2bf(v1.y), f2bf(v1.z), f2bf(v1.w)};
      *(uint4*)&Ws[c][c16] = *(const uint4*)&tmp[0];
    }
    __syncthreads();
    const bf16x8 a0 = *(const bf16x8*)&Xs[rs * 16 + lrow][g * 8];
    const bf16x8 a1 = *(const bf16x8*)&Xs[rs * 16 + lrow][32 + g * 8];
#pragma unroll
    for (int sub = 0; sub < 3; ++sub) {
      const int c = (ws2 * 3 + sub) * 16 + lrow;
      const bf16x8 b0 = *(const bf16x8*)&Ws[c][g * 8];
      const bf16x8 b1 = *(const bf16x8*)&Ws[c][32 + g * 8];
      acc[sub] = __builtin_amdgcn_mfma_f32_16x16x32_bf16(b0, a0, acc[sub], 0, 0, 0);
      acc[sub] = __builtin_amdgcn_mfma_f32_16x16x32_bf16(b1, a1, acc[sub], 0, 0, 0);
    }
  }
  const int n = r0 + rs * 16 + lrow;
#pragma unroll
  for (int sub = 0; sub < 3; ++sub) {
    u16 o4[4] = {f2bf(acc[sub][0]), f2bf(acc[sub][1]),
                 f2bf(acc[sub][2]), f2bf(acc[sub][3])};
    *(uint2*)&t_bf[(size_t)n * 96 + (ws2 * 3 + sub) * 16 + g * 4] = *(const uint2*)o4;
  }
}

// K2: q/k/v projections, MFMA with swapped operands -> coalesced stores.
__global__ __launch_bounds__(256) void k_proj2(const u16* __restrict__ t_bf,
                                               const float* __restrict__ qw2,
                                               const float* __restrict__ kvw2,
                                               u16* __restrict__ qb,
                                               u16* __restrict__ kb,
                                               float* __restrict__ vh) {
  __shared__ __align__(16) u16 Ts[64][72];
  __shared__ __align__(16) u16 Wsh[128][72];
  const int cb = blockIdx.x % 12;
  const int r0 = (blockIdx.x / 12) * 64;
  const int tid = threadIdx.x;
  const int wave = tid >> 6, lane = tid & 63;
  const int lrow = lane & 15, g = lane >> 4;
  const bool isq = cb < 4;
  const int c0 = isq ? cb * 128 : 512 + (cb - 4) * 128;

  for (int u = tid; u < 512; u += 256) {
    const int row = u >> 3, ch = (u & 7) * 8;
    uint4 v = {0u, 0u, 0u, 0u};
    if (isq) {
      if (ch < 32) v = *(const uint4*)&t_bf[(size_t)(r0 + row) * 96 + ch];
    } else {
      v = *(const uint4*)&t_bf[(size_t)(r0 + row) * 96 + 32 + ch];
    }
    *(uint4*)&Ts[row][ch] = v;
  }
  if (isq) {
    for (int u = tid; u < 1024; u += 256) {
      const int col = u >> 3, cf = (u & 7) * 4;
      const float4 v = *(const float4*)&qw2[(size_t)(c0 + col) * 32 + cf];
      u16 tmp[4] = {f2bf(v.x), f2bf(v.y), f2bf(v.z), f2bf(v.w)};
      *(uint2*)&Wsh[col][cf] = *(const uint2*)&tmp[0];
    }
  } else {
    for (int u = tid; u < 2048; u += 256) {
      const int col = u >> 4, cf = (u & 15) * 4;
      const float4 v = *(const float4*)&kvw2[(size_t)(c0 - 512 + col) * 64 + cf];
      u16 tmp[4] = {f2bf(v.x), f2bf(v.y), f2bf(v.z), f2bf(v.w)};
      *(uint2*)&Wsh[col][cf] = *(const uint2*)&tmp[0];
    }
  }
  __syncthreads();

  const int n = r0 + wave * 16 + lrow;
  if (isq) {
    const bf16x8 aq = *(const bf16x8*)&Ts[wave * 16 + lrow][g * 8];
#pragma unroll
    for (int sub = 0; sub < 8; ++sub) {
      const bf16x8 b0 = *(const bf16x8*)&Wsh[sub * 16 + lrow][g * 8];
      f32x4 acc = {0.f, 0.f, 0.f, 0.f};
      acc = __builtin_amdgcn_mfma_f32_16x16x32_bf16(b0, aq, acc, 0, 0, 0);
      const int colg0 = c0 + sub * 16 + g * 4;
      const int hh = colg0 >> 6, d0 = colg0 & 63;
      u16 o4[4] = {f2bf(acc[0] * QSCALE), f2bf(acc[1] * QSCALE),
                   f2bf(acc[2] * QSCALE), f2bf(acc[3] * QSCALE)};
      *(uint2*)&qb[((size_t)hh * NFULL + n) * 64 + d0] = *(const uint2*)o4;
    }
  } else {
    const bf16x8 a0 = *(const bf16x8*)&Ts[wave * 16 + lrow][g * 8];
    const bf16x8 a1 = *(const bf16x8*)&Ts[wave * 16 + lrow][32 + g * 8];
#pragma unroll
    for (int sub = 0; sub < 8; ++sub) {
      const bf16x8 b0 = *(const bf16x8*)&Wsh[sub * 16 + lrow][g * 8];
      const bf16x8 b1 = *(const bf16x8*)&Wsh[sub * 16 + lrow][32 + g * 8];
      f32x4 acc = {0.f, 0.f, 0.f, 0.f};
      acc = __builtin_amdgcn_mfma_f32_16x16x32_bf16(b0, a0, acc, 0, 0, 0);
      acc = __builtin_amdgcn_mfma_f32_16x16x32_bf16(b1, a1, acc, 0, 0, 0);
      const int colg0 = c0 + sub * 16 + g * 4;
      if (colg0 < 1024) {
        const int c2 = colg0 - 512;
        const int hh = c2 >> 6, d0 = c2 & 63;
        u16 o4[4] = {f2bf(acc[0]), f2bf(acc[1]), f2bf(acc[2]), f2bf(acc[3])};
        *(uint2*)&kb[((size_t)hh * NFULL + n) * 64 + d0] = *(const uint2*)o4;
      } else {
        const int c2 = colg0 - 1024;
        const int hh = c2 >> 6, d0 = c2 & 63;
        float4 o4;
        o4.x = acc[0]; o4.y = acc[1]; o4.z = acc[2]; o4.w = acc[3];
        *(float4*)&vh[((size_t)hh * NFULL + n) * 64 + d0] = o4;
      }
    }
  }
}

// K3: attention (R12-verified structure). Block (h, qt, s): 64 queries, keys
// [s*2048,+2048) in 32 tiles. Wave-private global_load_lds staging, 4-deep
// circular swizzled LDS buffer, counted vmcnt, no main-loop barriers.
__global__ __launch_bounds__(256, 4) void k_attn(const u16* __restrict__ qb,
                                                 const u16* __restrict__ kb,
                                                 const float* __restrict__ vh,
                                                 u16* __restrict__ wv16,
                                                 float* __restrict__ dsp) {
  __shared__ __align__(16) u16 KB[4][64][64];
  __shared__ float P_lds[4][16][17];
  __shared__ float Ds[4][4][16];

  const int h = blockIdx.x & 7;
  const int qt = (blockIdx.x >> 3) & 63;
  const int s = blockIdx.x >> 9;
  const int q0 = qt * 64;
  const int tid = threadIdx.x;
  const int wave = tid >> 6, lane = tid & 63;
  const int lrow = lane & 15, g = lane >> 4;

  const u16* __restrict__ Qg = qb + ((size_t)h * NFULL + q0) * 64;
  const u16* __restrict__ Kg = kb + ((size_t)h * NFULL + (size_t)s * 2048) * 64;

  bf16x8 qf[4][2];
#pragma unroll
  for (int f = 0; f < 4; ++f) {
    qf[f][0] = *(const bf16x8*)&Qg[(f * 16 + lrow) * 64 + g * 8];
    qf[f][1] = *(const bf16x8*)&Qg[(f * 16 + lrow) * 64 + 32 + g * 8];
  }

  const int srow8 = lane >> 3;
  const int scol = ((lane & 7) ^ srow8) << 3;

#define STAGE(T, B)                                                           \
  do {                                                                        \
    const u16* tb_ = Kg + (size_t)(T) * 64 * 64;                              \
    {                                                                         \
      const u16* src_ = tb_ + (wave * 16 + srow8) * 64 + scol;                \
      u16* dst_ = &KB[(B)][wave * 16][0];                                     \
      __builtin_amdgcn_global_load_lds(                                       \
          (const __attribute__((address_space(1))) unsigned*)src_,            \
          (__attribute__((address_space(3))) unsigned*)dst_, 16, 0, 0);       \
    }                                                                         \
    {                                                                         \
      const u16* src_ = tb_ + (wave * 16 + 8 + srow8) * 64 + scol;            \
      u16* dst_ = &KB[(B)][wave * 16][0] + 512;                               \
      __builtin_amdgcn_global_load_lds(                                       \
          (const __attribute__((address_space(1))) unsigned*)src_,            \
          (__attribute__((address_space(3))) unsigned*)dst_, 16, 0, 0);       \
    }                                                                         \
  } while (0)

  const int rsw = wave * 16 + lrow;
  const int x0 = (g ^ (lrow & 7)) * 8;
  const int x1 = ((g + 4) ^ (lrow & 7)) * 8;

  float dsum[4] = {0.f, 0.f, 0.f, 0.f};
  const bool dg = (s == (qt >> 5));
  const int tdiag = qt & 31;

  auto tile = [&](int t, int b) {
    const bf16x8 kf0 = *(const bf16x8*)&KB[b][rsw][x0];
    const bf16x8 kf1 = *(const bf16x8*)&KB[b][rsw][x1];
    f32x4 a[4];
    __builtin_amdgcn_s_setprio(1);
#pragma unroll
    for (int f = 0; f < 4; ++f) {
      f32x4 t4 = {0.f, 0.f, 0.f, 0.f};
      t4 = __builtin_amdgcn_mfma_f32_16x16x32_bf16(kf0, qf[f][0], t4, 0, 0, 0);
      t4 = __builtin_amdgcn_mfma_f32_16x16x32_bf16(kf1, qf[f][1], t4, 0, 0, 0);
      a[f] = t4;
    }
    __builtin_amdgcn_s_setprio(0);
    const bool isd = dg && (t == tdiag);
#pragma unroll
    for (int f = 0; f < 4; ++f) {
      const float e0 = EXP2(a[f][0]);
      const float e1 = EXP2(a[f][1]);
      const float e2 = EXP2(a[f][2]);
      const float e3 = EXP2(a[f][3]);
      dsum[f] += (e0 + e1) + (e2 + e3);
      if (isd && f == wave) {
        const int rr = g * 4;
        P_lds[wave][rr + 0][lrow] = (rr + 0 <= lrow) ? e0 : 0.f;
        P_lds[wave][rr + 1][lrow] = (rr + 1 <= lrow) ? e1 : 0.f;
        P_lds[wave][rr + 2][lrow] = (rr + 2 <= lrow) ? e2 : 0.f;
        P_lds[wave][rr + 3][lrow] = (rr + 3 <= lrow) ? e3 : 0.f;
      }
    }
  };

  STAGE(0, 0); STAGE(1, 1); STAGE(2, 2);

  for (int t = 0; t < 28; t += 2) {
    STAGE(t + 3, (t + 3) & 3);
    asm volatile("s_waitcnt vmcnt(6)" ::: "memory");
    tile(t, t & 3);
    STAGE(t + 4, (t + 4) & 3);
    asm volatile("s_waitcnt vmcnt(6)" ::: "memory");
    tile(t + 1, (t + 1) & 3);
  }
  STAGE(31, 3);
  asm volatile("s_waitcnt vmcnt(6)" ::: "memory");
  tile(28, 0);
  asm volatile("s_waitcnt vmcnt(4)" ::: "memory");
  tile(29, 1);
  asm volatile("s_waitcnt vmcnt(2)" ::: "memory");
  tile(30, 2);
  asm volatile("s_waitcnt vmcnt(0)" ::: "memory");
  tile(31, 3);
#undef STAGE

#pragma unroll
  for (int f = 0; f < 4; ++f) {
    dsum[f] += __shfl_xor(dsum[f], 16);
    dsum[f] += __shfl_xor(dsum[f], 32);
  }
  if (g == 0) {
#pragma unroll
    for (int f = 0; f < 4; ++f) Ds[wave][f][lrow] = dsum[f];
  }
  __syncthreads();

  if (tid < 64) {
    const int f = tid >> 4, r = tid & 15;
    const float den = Ds[0][f][r] + Ds[1][f][r] + Ds[2][f][r] + Ds[3][f][r];
    dsp[((size_t)s * HEADS + h) * NFULL + q0 + f * 16 + r] = den;
  }

  if (dg) {
    const float* __restrict__ V =
        vh + ((size_t)h * NFULL + q0 + wave * 16) * 64 + g * 16;
    float o[16];
#pragma unroll
    for (int dd = 0; dd < 16; ++dd) o[dd] = 0.f;
#pragma unroll
    for (int k = 0; k < 16; ++k) {
      const float p = P_lds[wave][k][lrow];
      const float4 v0 = *(const float4*)&V[k * 64 + 0];
      const float4 v1 = *(const float4*)&V[k * 64 + 4];
      const float4 v2 = *(const float4*)&V[k * 64 + 8];
      const float4 v3 = *(const float4*)&V[k * 64 + 12];
      o[0] += p * v0.x;  o[1] += p * v0.y;  o[2] += p * v0.z;  o[3] += p * v0.w;
      o[4] += p * v1.x;  o[5] += p * v1.y;  o[6] += p * v1.z;  o[7] += p * v1.w;
      o[8] += p * v2.x;  o[9] += p * v2.y;  o[10] += p * v2.z; o[11] += p * v2.w;
      o[12] += p * v3.x; o[13] += p * v3.y; o[14] += p * v3.z; o[15] += p * v3.w;
    }
    u16 ob[16];
#pragma unroll
    for (int dd = 0; dd < 16; ++dd) ob[dd] = f2bf(o[dd]);
    u16* __restrict__ op =
        wv16 + (size_t)(q0 + wave * 16 + lrow) * CDIM + h * 64 + g * 16;
    *(uint4*)&op[0] = *(const uint4*)&ob[0];
    *(uint4*)&op[8] = *(const uint4*)&ob[8];
  }
}

// K4: y16 = bf16(normalize(wv16) @ pwbf^T + bias2 + x); denom = 2 dsp splits.
__global__ __launch_bounds__(256) void k_dyn(const u16* __restrict__ wv16,
                                             const float* __restrict__ x,
                                             const u16* __restrict__ pwbf,
                                             const float* __restrict__ bias2,
                                             const float* __restrict__ dsp,
                                             u16* __restrict__ y16) {
  __shared__ __align__(16) u16 Ab[64][72];
  __shared__ __align__(16) u16 Wb[64][72];
  const int rb = blockIdx.x >> 3, cb = blockIdx.x & 7;
  const int r0 = rb * 64, c0 = cb * 64;
  const int tid = threadIdx.x;
  const int wave = tid >> 6, lane = tid & 63;
  const int lrow = lane & 15, g = lane >> 4;
  const int srow = tid >> 2;
  const int skc = (tid & 3) * 16;

  float inv8[8];
#pragma unroll
  for (int hh = 0; hh < 8; ++hh) {
    const size_t base = (size_t)hh * NFULL + r0 + srow;
    inv8[hh] = 1.0f / (dsp[base] + dsp[(size_t)8 * NFULL + base]);
  }

  f32x4 acc[4];
#pragma unroll
  for (int ct = 0; ct < 4; ++ct) acc[ct] = (f32x4){0.f, 0.f, 0.f, 0.f};

  const u16* __restrict__ ap = wv16 + (size_t)(r0 + srow) * 512 + skc;
  const u16* __restrict__ wp = pwbf + (size_t)(c0 + srow) * 512 + skc;
  uint4 av0 = *(const uint4*)ap;
  uint4 av1 = *(const uint4*)(ap + 8);
  uint4 w0 = *(const uint4*)wp;
  uint4 w1 = *(const uint4*)(wp + 8);

  for (int k0 = 0; k0 < 512; k0 += 64) {
    const float sc = inv8[k0 >> 6];
    u16 ab16[16];
    const u16* pa0 = (const u16*)&av0;
    const u16* pa1 = (const u16*)&av1;
#pragma unroll
    for (int e = 0; e < 8; ++e) ab16[e] = f2bf(bf2f(pa0[e]) * sc);
#pragma unroll
    for (int e = 0; e < 8; ++e) ab16[8 + e] = f2bf(bf2f(pa1[e]) * sc);
    __syncthreads();
    *(uint4*)&Ab[srow][skc] = *(const uint4*)&ab16[0];
    *(uint4*)&Ab[srow][skc + 8] = *(const uint4*)&ab16[8];
    *(uint4*)&Wb[srow][skc] = w0;
    *(uint4*)&Wb[srow][skc + 8] = w1;
    __syncthreads();
    if (k0 + 64 < 512) {
      av0 = *(const uint4*)(ap + k0 + 64);
      av1 = *(const uint4*)(ap + k0 + 64 + 8);
      w0 = *(const uint4*)(wp + k0 + 64);
      w1 = *(const uint4*)(wp + k0 + 64 + 8);
    }
#pragma unroll
    for (int kk = 0; kk < 2; ++kk) {
      const bf16x8 af = *(const bf16x8*)&Ab[wave * 16 + lrow][kk * 32 + g * 8];
#pragma unroll
      for (int ct = 0; ct < 4; ++ct) {
        const bf16x8 wf = *(const bf16x8*)&Wb[ct * 16 + lrow][kk * 32 + g * 8];
        acc[ct] = __builtin_amdgcn_mfma_f32_16x16x32_bf16(wf, af, acc[ct], 0, 0, 0);
      }
    }
  }
  const int row = r0 + wave * 16 + lrow;
#pragma unroll
  for (int ct = 0; ct < 4; ++ct) {
    const int c = c0 + ct * 16 + g * 4;
    const float4 bb = *(const float4*)&bias2[c];
    const float4 xv = *(const float4*)&x[(size_t)row * 512 + c];
    u16 o4[4];
    o4[0] = f2bf(acc[ct][0] + bb.x + xv.x);
    o4[1] = f2bf(acc[ct][1] + bb.y + xv.y);
    o4[2] = f2bf(acc[ct][2] + bb.z + xv.z);
    o4[3] = f2bf(acc[ct][3] + bb.w + xv.w);
    *(uint2*)&y16[(size_t)row * 512 + c] = *(const uint2*)o4;
  }
}

// K5: out = ((y @ p_w1^T) @ p_w2^T) fused via MFMA. Grid 512 = 256 row-tiles
// x 2 col-halves.
__global__ __launch_bounds__(256) void k_pout(const u16* __restrict__ y16,
                                              const u16* __restrict__ pw1bf,
                                              const u16* __restrict__ pw2bf,
                                              float* __restrict__ out) {
  __shared__ __align__(16) u16 yb[16][520];
  __shared__ float tp_part[2][32][17];
  const int r0 = (blockIdx.x >> 1) * 16;
  const int chalf = blockIdx.x & 1;
  const int tid = threadIdx.x;
  const int wave = tid >> 6, lane = tid & 63;
  const int lrow = lane & 15, g = lane >> 4;

  for (int rep = 0; rep < 4; ++rep) {
    const int idx = rep * 256 + tid;
    const int row = idx >> 6, c8 = (idx & 63) * 8;
    *(uint4*)&yb[row][c8] = *(const uint4*)&y16[(size_t)(r0 + row) * 512 + c8];
  }
  __syncthreads();

  {
    const int ct1 = wave & 1, kh = wave >> 1;
    f32x4 acc = {0.f, 0.f, 0.f, 0.f};
#pragma unroll
    for (int ks = 0; ks < 8; ++ks) {
      const int K = kh * 256 + ks * 32 + g * 8;
      const bf16x8 aw = *(const bf16x8*)&pw1bf[(size_t)(ct1 * 16 + lrow) * 512 + K];
      const bf16x8 bf = *(const bf16x8*)&yb[lrow][K];
      acc = __builtin_amdgcn_mfma_f32_16x16x32_bf16(aw, bf, acc, 0, 0, 0);
    }
#pragma unroll
    for (int j = 0; j < 4; ++j)
      tp_part[kh][ct1 * 16 + g * 4 + j][lrow] = acc[j];
  }
  __syncthreads();

  union { u16 a[8]; bf16x8 v; } bq;
#pragma unroll
  for (int i = 0; i < 8; ++i) {
    const int k = g * 8 + i;
    bq.a[i] = f2bf(tp_part[0][k][lrow] + tp_part[1][k][lrow]);
  }

#pragma unroll
  for (int t = 0; t < 4; ++t) {
    const int ct = chalf * 16 + wave * 4 + t;
    const bf16x8 aw = *(const bf16x8*)&pw2bf[(size_t)(ct * 16 + lrow) * 32 + g * 8];
    f32x4 acc = {0.f, 0.f, 0.f, 0.f};
    acc = __builtin_amdgcn_mfma_f32_16x16x32_bf16(aw, bq.v, acc, 0, 0, 0);
    float4 res;
    res.x = acc[0]; res.y = acc[1]; res.z = acc[2]; res.w = acc[3];
    *(float4*)&out[(size_t)(r0 + lrow) * 512 + ct * 16 + g * 4] = res;
  }
}

extern "C" void kernel_launch(void* const* d_in, const int* in_sizes, int n_in,
                              void* d_out, int out_size, void* d_ws, size_t ws_size,
                              hipStream_t stream) {
  const float* x     = (const float*)d_in[0];
  const float* q_w1  = (const float*)d_in[1];
  const float* q_w2  = (const float*)d_in[2];
  const float* kv_w1 = (const float*)d_in[3];
  const float* kv_w2 = (const float*)d_in[4];
  const float* dw_w  = (const float*)d_in[5];
  const float* dw_b  = (const float*)d_in[6];
  const float* pw_w  = (const float*)d_in[7];
  const float* pw_b  = (const float*)d_in[8];
  const float* p_w1  = (const float*)d_in[9];
  const float* p_w2  = (const float*)d_in[10];
  float* out = (float*)d_out;

  char* ws = (char*)d_ws;
  float* dsp   = (float*)ws;                      // 2*8*4096 f32 (256KB)
  float* bias2 = (float*)(ws + 262144);           // 1024 f32 (4KB)
  u16*   pwbf  = (u16*)(ws + 262144 + 4096);      // 512*512 u16 (512KB)
  u16*   pw1bf = pwbf + 262144;                   // 16384 u16 (32KB)
  u16*   pw2bf = pw1bf + 16384;                   // 16384 u16 (32KB)
  u16*   t_bf  = pw2bf + 16384;                   // 4096*96 u16 (768KB)
  u16*   qbw   = t_bf + (size_t)NFULL * 96;       // 2M u16 (4MB)
  u16*   kbw   = qbw + (size_t)HEADS * NFULL * DDIM;  // 2M u16 (4MB)
  float* vh    = (float*)(kbw + (size_t)HEADS * NFULL * DDIM);  // 2M f32 (8MB)
  u16*   wv16  = (u16*)(vh + (size_t)HEADS * NFULL * DDIM);     // 2M u16 (4MB)
  u16*   y16   = qbw;  // alias (qb dead after k_attn)

  k_pre<<<202, 256, 0, stream>>>(x, q_w1, kv_w1, t_bf, pw_w, dw_w, dw_b, pw_b,
                                 p_w1, p_w2, bias2, pwbf, pw1bf, pw2bf);
  k_proj2<<<(NFULL / 64) * 12, 256, 0, stream>>>(t_bf, q_w2, kv_w2, qbw, kbw, vh);
  k_attn<<<2 * HEADS * (NFULL / 64), 256, 0, stream>>>(qbw, kbw, vh, wv16, dsp);
  k_dyn<<<(NFULL / 64) * 8, 256, 0, stream>>>(wv16, x, pwbf, bias2, dsp, y16);
  k_pout<<<(NFULL / 16) * 2, 256, 0, stream>>>(y16, pw1bf, pw2bf, out);
}

// Round 16
// 83.296 us; speedup vs baseline: 1.9366x; 1.0153x over previous
//
#include <hip/hip_runtime.h>

#define NFULL 4096
#define CDIM  512
#define HEADS 8
#define DDIM  64

typedef unsigned short u16;
typedef short bf16x8 __attribute__((ext_vector_type(8)));
typedef float f32x4 __attribute__((ext_vector_type(4)));

#if __has_builtin(__builtin_amdgcn_exp2f)
__device__ __forceinline__ float exp2_hw(float x) { return __builtin_amdgcn_exp2f(x); }
#else
__device__ __forceinline__ float exp2_hw(float x) {
  float r;
  asm volatile("v_exp_f32 %0, %1\n\ts_nop 1" : "=v"(r) : "v"(x));
  return r;
}
#endif
#define EXP2(x) exp2_hw(x)

// q pre-scaled by SCALE * log2(e) so exp(s) == exp2(s').
#define QSCALE 11.541560327111707f  // 8 * 1.4426950408889634

__device__ __forceinline__ float dot4(float4 a, float4 b) {
  return a.x * b.x + a.y * b.y + a.z * b.z + a.w * b.w;
}

__device__ __forceinline__ u16 f2bf(float x) {  // RNE f32 -> bf16 bits
  union { float f; unsigned u; } v; v.f = x;
  unsigned r = v.u + 0x7fffu + ((v.u >> 16) & 1u);
  return (u16)(r >> 16);
}

__device__ __forceinline__ float bf2f(u16 b) {
  union { unsigned u; float f; } v; v.u = ((unsigned)b) << 16;
  return v.f;
}

// K1: blocks 0..127: t_bf[32 rows][96] = bf16(x @ [q_w1;kv_w1]^T), MFMA,
// coalesced stores via swapped operands. 128..129: bias2. 130..193: pwbf.
// 194..197: pw1bf. 198..201: pw2bf.
__global__ __launch_bounds__(256) void k_pre(const float* __restrict__ x,
                                             const float* __restrict__ qw1,
                                             const float* __restrict__ kvw1,
                                             u16* __restrict__ t_bf,
                                             const float* __restrict__ pww,
                                             const float* __restrict__ dww,
                                             const float* __restrict__ dwb,
                                             const float* __restrict__ pwb,
                                             const float* __restrict__ pw1,
                                             const float* __restrict__ pw2,
                                             float* __restrict__ bias2,
                                             u16* __restrict__ pwbf,
                                             u16* __restrict__ pw1bf,
                                             u16* __restrict__ pw2bf) {
  __shared__ __align__(16) u16 Xs[32][72];
  __shared__ __align__(16) u16 Ws[96][72];
  const int tid = threadIdx.x;

  if (blockIdx.x >= 128) {  // weight prep
    const int b = blockIdx.x - 128;
    if (b < 2) {
      const int c = b * 256 + tid;
      float acc = 0.f;
      for (int e = 0; e < 512; e += 4)
        acc += dot4(*(const float4*)&pww[(size_t)c * 512 + e], *(const float4*)&dwb[e]);
      bias2[c] = acc + pwb[c];
    } else {
      const float* src;
      u16* dst;
      bool scale = false;
      int base;
      if (b < 66)      { base = (b - 2) * 4096 + tid * 16;  src = pww; dst = pwbf; scale = true; }
      else if (b < 70) { base = (b - 66) * 4096 + tid * 16; src = pw1; dst = pw1bf; }
      else             { base = (b - 70) * 4096 + tid * 16; src = pw2; dst = pw2bf; }
      const int e0 = base & 511;
      u16 o[16];
#pragma unroll
      for (int q = 0; q < 4; ++q) {
        float4 w = *(const float4*)&src[base + q * 4];
        if (scale) {
          const float4 d = *(const float4*)&dww[e0 + q * 4];
          w.x *= d.x; w.y *= d.y; w.z *= d.z; w.w *= d.w;
        }
        o[q * 4 + 0] = f2bf(w.x); o[q * 4 + 1] = f2bf(w.y);
        o[q * 4 + 2] = f2bf(w.z); o[q * 4 + 3] = f2bf(w.w);
      }
      *(uint4*)&dst[base] = *(const uint4*)&o[0];
      *(uint4*)&dst[base + 8] = *(const uint4*)&o[8];
    }
    return;
  }

  const int r0 = blockIdx.x * 32;
  const int wave = tid >> 6, lane = tid & 63;
  const int lrow = lane & 15, g = lane >> 4;
  const int rs = wave >> 1, ws2 = wave & 1;

  f32x4 acc[3];
#pragma unroll
  for (int sub = 0; sub < 3; ++sub) acc[sub] = (f32x4){0.f, 0.f, 0.f, 0.f};

  for (int k0 = 0; k0 < 512; k0 += 64) {
    __syncthreads();
    {
      const int row = tid >> 3, c16 = (tid & 7) * 8;
      const float* __restrict__ src = x + (size_t)(r0 + row) * 512 + k0 + c16;
      const float4 v0 = *(const float4*)(src);
      const float4 v1 = *(const float4*)(src + 4);
      u16 tmp[8] = {f2bf(v0.x), f2bf(v0.y), f2bf(v0.z), f2bf(v0.w),
                    f2bf(v1.x), f2bf(v1.y), f2bf(v1.z), f2bf(v1.w)};
      *(uint4*)&Xs[row][c16] = *(const uint4*)&tmp[0];
    }
    for (int u = tid; u < 768; u += 256) {
      const int c = u >> 3, c16 = (u & 7) * 8;
      const float* __restrict__ src =
          (c < 32 ? qw1 + (size_t)c * 512 : kvw1 + (size_t)(c - 32) * 512) + k0 + c16;
      const float4 v0 = *(const float4*)(src);
      const float4 v1 = *(const float4*)(src + 4);
      u16 tmp[8] = {f2bf(v0.x), f2bf(v0.y), f2bf(v0.z), f2bf(v0.w),
                    f2bf(v1.x), f2bf(v1.y), f2bf(v1.z), f2bf(v1.w)};
      *(uint4*)&Ws[c][c16] = *(const uint4*)&tmp[0];
    }
    __syncthreads();
    const bf16x8 a0 = *(const bf16x8*)&Xs[rs * 16 + lrow][g * 8];
    const bf16x8 a1 = *(const bf16x8*)&Xs[rs * 16 + lrow][32 + g * 8];
#pragma unroll
    for (int sub = 0; sub < 3; ++sub) {
      const int c = (ws2 * 3 + sub) * 16 + lrow;
      const bf16x8 b0 = *(const bf16x8*)&Ws[c][g * 8];
      const bf16x8 b1 = *(const bf16x8*)&Ws[c][32 + g * 8];
      acc[sub] = __builtin_amdgcn_mfma_f32_16x16x32_bf16(b0, a0, acc[sub], 0, 0, 0);
      acc[sub] = __builtin_amdgcn_mfma_f32_16x16x32_bf16(b1, a1, acc[sub], 0, 0, 0);
    }
  }
  const int n = r0 + rs * 16 + lrow;
#pragma unroll
  for (int sub = 0; sub < 3; ++sub) {
    u16 o4[4] = {f2bf(acc[sub][0]), f2bf(acc[sub][1]),
                 f2bf(acc[sub][2]), f2bf(acc[sub][3])};
    *(uint2*)&t_bf[(size_t)n * 96 + (ws2 * 3 + sub) * 16 + g * 4] = *(const uint2*)o4;
  }
}

// K2: q/k/v projections, MFMA with swapped operands -> coalesced stores.
__global__ __launch_bounds__(256) void k_proj2(const u16* __restrict__ t_bf,
                                               const float* __restrict__ qw2,
                                               const float* __restrict__ kvw2,
                                               u16* __restrict__ qb,
                                               u16* __restrict__ kb,
                                               float* __restrict__ vh) {
  __shared__ __align__(16) u16 Ts[64][72];
  __shared__ __align__(16) u16 Wsh[128][72];
  const int cb = blockIdx.x % 12;
  const int r0 = (blockIdx.x / 12) * 64;
  const int tid = threadIdx.x;
  const int wave = tid >> 6, lane = tid & 63;
  const int lrow = lane & 15, g = lane >> 4;
  const bool isq = cb < 4;
  const int c0 = isq ? cb * 128 : 512 + (cb - 4) * 128;

  for (int u = tid; u < 512; u += 256) {
    const int row = u >> 3, ch = (u & 7) * 8;
    uint4 v = {0u, 0u, 0u, 0u};
    if (isq) {
      if (ch < 32) v = *(const uint4*)&t_bf[(size_t)(r0 + row) * 96 + ch];
    } else {
      v = *(const uint4*)&t_bf[(size_t)(r0 + row) * 96 + 32 + ch];
    }
    *(uint4*)&Ts[row][ch] = v;
  }
  if (isq) {
    for (int u = tid; u < 1024; u += 256) {
      const int col = u >> 3, cf = (u & 7) * 4;
      const float4 v = *(const float4*)&qw2[(size_t)(c0 + col) * 32 + cf];
      u16 tmp[4] = {f2bf(v.x), f2bf(v.y), f2bf(v.z), f2bf(v.w)};
      *(uint2*)&Wsh[col][cf] = *(const uint2*)&tmp[0];
    }
  } else {
    for (int u = tid; u < 2048; u += 256) {
      const int col = u >> 4, cf = (u & 15) * 4;
      const float4 v = *(const float4*)&kvw2[(size_t)(c0 - 512 + col) * 64 + cf];
      u16 tmp[4] = {f2bf(v.x), f2bf(v.y), f2bf(v.z), f2bf(v.w)};
      *(uint2*)&Wsh[col][cf] = *(const uint2*)&tmp[0];
    }
  }
  __syncthreads();

  const int n = r0 + wave * 16 + lrow;
  if (isq) {
    const bf16x8 aq = *(const bf16x8*)&Ts[wave * 16 + lrow][g * 8];
#pragma unroll
    for (int sub = 0; sub < 8; ++sub) {
      const bf16x8 b0 = *(const bf16x8*)&Wsh[sub * 16 + lrow][g * 8];
      f32x4 acc = {0.f, 0.f, 0.f, 0.f};
      acc = __builtin_amdgcn_mfma_f32_16x16x32_bf16(b0, aq, acc, 0, 0, 0);
      const int colg0 = c0 + sub * 16 + g * 4;
      const int hh = colg0 >> 6, d0 = colg0 & 63;
      u16 o4[4] = {f2bf(acc[0] * QSCALE), f2bf(acc[1] * QSCALE),
                   f2bf(acc[2] * QSCALE), f2bf(acc[3] * QSCALE)};
      *(uint2*)&qb[((size_t)hh * NFULL + n) * 64 + d0] = *(const uint2*)o4;
    }
  } else {
    const bf16x8 a0 = *(const bf16x8*)&Ts[wave * 16 + lrow][g * 8];
    const bf16x8 a1 = *(const bf16x8*)&Ts[wave * 16 + lrow][32 + g * 8];
#pragma unroll
    for (int sub = 0; sub < 8; ++sub) {
      const bf16x8 b0 = *(const bf16x8*)&Wsh[sub * 16 + lrow][g * 8];
      const bf16x8 b1 = *(const bf16x8*)&Wsh[sub * 16 + lrow][32 + g * 8];
      f32x4 acc = {0.f, 0.f, 0.f, 0.f};
      acc = __builtin_amdgcn_mfma_f32_16x16x32_bf16(b0, a0, acc, 0, 0, 0);
      acc = __builtin_amdgcn_mfma_f32_16x16x32_bf16(b1, a1, acc, 0, 0, 0);
      const int colg0 = c0 + sub * 16 + g * 4;
      if (colg0 < 1024) {
        const int c2 = colg0 - 512;
        const int hh = c2 >> 6, d0 = c2 & 63;
        u16 o4[4] = {f2bf(acc[0]), f2bf(acc[1]), f2bf(acc[2]), f2bf(acc[3])};
        *(uint2*)&kb[((size_t)hh * NFULL + n) * 64 + d0] = *(const uint2*)o4;
      } else {
        const int c2 = colg0 - 1024;
        const int hh = c2 >> 6, d0 = c2 & 63;
        float4 o4;
        o4.x = acc[0]; o4.y = acc[1]; o4.z = acc[2]; o4.w = acc[3];
        *(float4*)&vh[((size_t)hh * NFULL + n) * 64 + d0] = o4;
      }
    }
  }
}

// K3: attention, 128-query blocks with R12's wave-private no-barrier staging.
// Block (h, qt, s): 128 queries (q0=qt*128), keys [s*2048,+2048) in 32 tiles.
// Each wave stages rows wave*16..+16 of each tile (identical to R12) and MFMAs
// them vs 8 Q-subtiles -> K traffic halved vs 64-query blocks. Grid 512.
__global__ __launch_bounds__(256, 2) void k_attn(const u16* __restrict__ qb,
                                                 const u16* __restrict__ kb,
                                                 const float* __restrict__ vh,
                                                 u16* __restrict__ wv16,
                                                 float* __restrict__ dsp) {
  __shared__ __align__(16) u16 KB[4][64][64];  // 32 KB, rows XOR-swizzled
  __shared__ float P_lds[8][16][17];
  __shared__ float Ds[4][8][16];

  const int h = blockIdx.x & 7;            // XCD affinity
  const int qt = (blockIdx.x >> 3) & 31;   // 128-query tile
  const int s = blockIdx.x >> 8;           // 0..1
  const int q0 = qt * 128;
  const int tid = threadIdx.x;
  const int wave = tid >> 6, lane = tid & 63;
  const int lrow = lane & 15, g = lane >> 4;

  const u16* __restrict__ Qg = qb + ((size_t)h * NFULL + q0) * 64;
  const u16* __restrict__ Kg = kb + ((size_t)h * NFULL + (size_t)s * 2048) * 64;

  bf16x8 qf[8][2];
#pragma unroll
  for (int j = 0; j < 8; ++j) {
    qf[j][0] = *(const bf16x8*)&Qg[(j * 16 + lrow) * 64 + g * 8];
    qf[j][1] = *(const bf16x8*)&Qg[(j * 16 + lrow) * 64 + 32 + g * 8];
  }

  const int srow8 = lane >> 3;
  const int scol = ((lane & 7) ^ srow8) << 3;

#define STAGE(T, B)                                                           \
  do {                                                                        \
    const u16* tb_ = Kg + (size_t)(T) * 64 * 64;                              \
    {                                                                         \
      const u16* src_ = tb_ + (wave * 16 + srow8) * 64 + scol;                \
      u16* dst_ = &KB[(B)][wave * 16][0];                                     \
      __builtin_amdgcn_global_load_lds(                                       \
          (const __attribute__((address_space(1))) unsigned*)src_,            \
          (__attribute__((address_space(3))) unsigned*)dst_, 16, 0, 0);       \
    }                                                                         \
    {                                                                         \
      const u16* src_ = tb_ + (wave * 16 + 8 + srow8) * 64 + scol;            \
      u16* dst_ = &KB[(B)][wave * 16][0] + 512;                               \
      __builtin_amdgcn_global_load_lds(                                       \
          (const __attribute__((address_space(1))) unsigned*)src_,            \
          (__attribute__((address_space(3))) unsigned*)dst_, 16, 0, 0);       \
    }                                                                         \
  } while (0)

  const int rsw = wave * 16 + lrow;
  const int x0 = (g ^ (lrow & 7)) * 8;
  const int x1 = ((g + 4) ^ (lrow & 7)) * 8;

  float dsum[8];
#pragma unroll
  for (int j = 0; j < 8; ++j) dsum[j] = 0.f;
  const bool dg = (s == (qt >> 4));
  const int ql = qt & 15;  // diag tiles: ql*2 (subs 0..3), ql*2+1 (subs 4..7)

  auto tile = [&](int t, int b) {
    const bf16x8 kf0 = *(const bf16x8*)&KB[b][rsw][x0];
    const bf16x8 kf1 = *(const bf16x8*)&KB[b][rsw][x1];
#pragma unroll
    for (int hs = 0; hs < 2; ++hs) {
      f32x4 a[4];
      __builtin_amdgcn_s_setprio(1);
#pragma unroll
      for (int f = 0; f < 4; ++f) {
        f32x4 t4 = {0.f, 0.f, 0.f, 0.f};
        t4 = __builtin_amdgcn_mfma_f32_16x16x32_bf16(kf0, qf[hs * 4 + f][0], t4, 0, 0, 0);
        t4 = __builtin_amdgcn_mfma_f32_16x16x32_bf16(kf1, qf[hs * 4 + f][1], t4, 0, 0, 0);
        a[f] = t4;
      }
      __builtin_amdgcn_s_setprio(0);
      const bool isd = dg && (t == ql * 2 + hs);
#pragma unroll
      for (int f = 0; f < 4; ++f) {
        const float e0 = EXP2(a[f][0]);
        const float e1 = EXP2(a[f][1]);
        const float e2 = EXP2(a[f][2]);
        const float e3 = EXP2(a[f][3]);
        dsum[hs * 4 + f] += (e0 + e1) + (e2 + e3);
        if (isd && f == wave) {  // wave w's keys == diag of q-sub hs*4+w
          const int rr = g * 4;
          const int J = hs * 4 + wave;
          P_lds[J][rr + 0][lrow] = (rr + 0 <= lrow) ? e0 : 0.f;
          P_lds[J][rr + 1][lrow] = (rr + 1 <= lrow) ? e1 : 0.f;
          P_lds[J][rr + 2][lrow] = (rr + 2 <= lrow) ? e2 : 0.f;
          P_lds[J][rr + 3][lrow] = (rr + 3 <= lrow) ? e3 : 0.f;
        }
      }
    }
  };

  STAGE(0, 0); STAGE(1, 1); STAGE(2, 2);

  for (int t = 0; t < 28; t += 2) {
    STAGE(t + 3, (t + 3) & 3);
    asm volatile("s_waitcnt vmcnt(6)" ::: "memory");
    tile(t, t & 3);
    STAGE(t + 4, (t + 4) & 3);
    asm volatile("s_waitcnt vmcnt(6)" ::: "memory");
    tile(t + 1, (t + 1) & 3);
  }
  STAGE(31, 3);
  asm volatile("s_waitcnt vmcnt(6)" ::: "memory");
  tile(28, 0);
  asm volatile("s_waitcnt vmcnt(4)" ::: "memory");
  tile(29, 1);
  asm volatile("s_waitcnt vmcnt(2)" ::: "memory");
  tile(30, 2);
  asm volatile("s_waitcnt vmcnt(0)" ::: "memory");
  tile(31, 3);
#undef STAGE

#pragma unroll
  for (int j = 0; j < 8; ++j) {  // reduce over key-row groups (g)
    dsum[j] += __shfl_xor(dsum[j], 16);
    dsum[j] += __shfl_xor(dsum[j], 32);
  }
  if (g == 0) {
#pragma unroll
    for (int j = 0; j < 8; ++j) Ds[wave][j][lrow] = dsum[j];
  }
  __syncthreads();

  if (tid < 128) {  // block-partial denominator for the 128 queries
    const int J2 = tid >> 4, r = tid & 15;
    const float den = Ds[0][J2][r] + Ds[1][J2][r] + Ds[2][J2][r] + Ds[3][J2][r];
    dsp[((size_t)s * HEADS + h) * NFULL + q0 + J2 * 16 + r] = den;
  }

  if (dg) {  // PV numerator (unnormalized bf16): wave handles subs wave, wave+4
#pragma unroll
    for (int m = 0; m < 2; ++m) {
      const int J = m * 4 + wave;
      const float* __restrict__ V =
          vh + ((size_t)h * NFULL + q0 + J * 16) * 64 + g * 16;
      float o[16];
#pragma unroll
      for (int dd = 0; dd < 16; ++dd) o[dd] = 0.f;
#pragma unroll
      for (int k = 0; k < 16; ++k) {
        const float p = P_lds[J][k][lrow];
        const float4 v0 = *(const float4*)&V[k * 64 + 0];
        const float4 v1 = *(const float4*)&V[k * 64 + 4];
        const float4 v2 = *(const float4*)&V[k * 64 + 8];
        const float4 v3 = *(const float4*)&V[k * 64 + 12];
        o[0] += p * v0.x;  o[1] += p * v0.y;  o[2] += p * v0.z;  o[3] += p * v0.w;
        o[4] += p * v1.x;  o[5] += p * v1.y;  o[6] += p * v1.z;  o[7] += p * v1.w;
        o[8] += p * v2.x;  o[9] += p * v2.y;  o[10] += p * v2.z; o[11] += p * v2.w;
        o[12] += p * v3.x; o[13] += p * v3.y; o[14] += p * v3.z; o[15] += p * v3.w;
      }
      u16 ob[16];
#pragma unroll
      for (int dd = 0; dd < 16; ++dd) ob[dd] = f2bf(o[dd]);
      u16* __restrict__ op =
          wv16 + (size_t)(q0 + J * 16 + lrow) * CDIM + h * 64 + g * 16;
      *(uint4*)&op[0] = *(const uint4*)&ob[0];
      *(uint4*)&op[8] = *(const uint4*)&ob[8];
    }
  }
}

// K4: y16 = bf16(normalize(wv16) @ pwbf^T + bias2 + x); denom = 2 dsp splits.
__global__ __launch_bounds__(256) void k_dyn(const u16* __restrict__ wv16,
                                             const float* __restrict__ x,
                                             const u16* __restrict__ pwbf,
                                             const float* __restrict__ bias2,
                                             const float* __restrict__ dsp,
                                             u16* __restrict__ y16) {
  __shared__ __align__(16) u16 Ab[64][72];
  __shared__ __align__(16) u16 Wb[64][72];
  const int rb = blockIdx.x >> 3, cb = blockIdx.x & 7;
  const int r0 = rb * 64, c0 = cb * 64;
  const int tid = threadIdx.x;
  const int wave = tid >> 6, lane = tid & 63;
  const int lrow = lane & 15, g = lane >> 4;
  const int srow = tid >> 2;
  const int skc = (tid & 3) * 16;

  float inv8[8];
#pragma unroll
  for (int hh = 0; hh < 8; ++hh) {
    const size_t base = (size_t)hh * NFULL + r0 + srow;
    inv8[hh] = 1.0f / (dsp[base] + dsp[(size_t)8 * NFULL + base]);
  }

  f32x4 acc[4];
#pragma unroll
  for (int ct = 0; ct < 4; ++ct) acc[ct] = (f32x4){0.f, 0.f, 0.f, 0.f};

  const u16* __restrict__ ap = wv16 + (size_t)(r0 + srow) * 512 + skc;
  const u16* __restrict__ wp = pwbf + (size_t)(c0 + srow) * 512 + skc;
  uint4 av0 = *(const uint4*)ap;
  uint4 av1 = *(const uint4*)(ap + 8);
  uint4 w0 = *(const uint4*)wp;
  uint4 w1 = *(const uint4*)(wp + 8);

  for (int k0 = 0; k0 < 512; k0 += 64) {
    const float sc = inv8[k0 >> 6];
    u16 ab16[16];
    const u16* pa0 = (const u16*)&av0;
    const u16* pa1 = (const u16*)&av1;
#pragma unroll
    for (int e = 0; e < 8; ++e) ab16[e] = f2bf(bf2f(pa0[e]) * sc);
#pragma unroll
    for (int e = 0; e < 8; ++e) ab16[8 + e] = f2bf(bf2f(pa1[e]) * sc);
    __syncthreads();
    *(uint4*)&Ab[srow][skc] = *(const uint4*)&ab16[0];
    *(uint4*)&Ab[srow][skc + 8] = *(const uint4*)&ab16[8];
    *(uint4*)&Wb[srow][skc] = w0;
    *(uint4*)&Wb[srow][skc + 8] = w1;
    __syncthreads();
    if (k0 + 64 < 512) {
      av0 = *(const uint4*)(ap + k0 + 64);
      av1 = *(const uint4*)(ap + k0 + 64 + 8);
      w0 = *(const uint4*)(wp + k0 + 64);
      w1 = *(const uint4*)(wp + k0 + 64 + 8);
    }
#pragma unroll
    for (int kk = 0; kk < 2; ++kk) {
      const bf16x8 af = *(const bf16x8*)&Ab[wave * 16 + lrow][kk * 32 + g * 8];
#pragma unroll
      for (int ct = 0; ct < 4; ++ct) {
        const bf16x8 wf = *(const bf16x8*)&Wb[ct * 16 + lrow][kk * 32 + g * 8];
        acc[ct] = __builtin_amdgcn_mfma_f32_16x16x32_bf16(wf, af, acc[ct], 0, 0, 0);
      }
    }
  }
  const int row = r0 + wave * 16 + lrow;
#pragma unroll
  for (int ct = 0; ct < 4; ++ct) {
    const int c = c0 + ct * 16 + g * 4;
    const float4 bb = *(const float4*)&bias2[c];
    const float4 xv = *(const float4*)&x[(size_t)row * 512 + c];
    u16 o4[4];
    o4[0] = f2bf(acc[ct][0] + bb.x + xv.x);
    o4[1] = f2bf(acc[ct][1] + bb.y + xv.y);
    o4[2] = f2bf(acc[ct][2] + bb.z + xv.z);
    o4[3] = f2bf(acc[ct][3] + bb.w + xv.w);
    *(uint2*)&y16[(size_t)row * 512 + c] = *(const uint2*)o4;
  }
}

// K5: out = ((y @ p_w1^T) @ p_w2^T) fused via MFMA. Grid 512 = 256 row-tiles
// x 2 col-halves.
__global__ __launch_bounds__(256) void k_pout(const u16* __restrict__ y16,
                                              const u16* __restrict__ pw1bf,
                                              const u16* __restrict__ pw2bf,
                                              float* __restrict__ out) {
  __shared__ __align__(16) u16 yb[16][520];
  __shared__ float tp_part[2][32][17];
  const int r0 = (blockIdx.x >> 1) * 16;
  const int chalf = blockIdx.x & 1;
  const int tid = threadIdx.x;
  const int wave = tid >> 6, lane = tid & 63;
  const int lrow = lane & 15, g = lane >> 4;

  for (int rep = 0; rep < 4; ++rep) {
    const int idx = rep * 256 + tid;
    const int row = idx >> 6, c8 = (idx & 63) * 8;
    *(uint4*)&yb[row][c8] = *(const uint4*)&y16[(size_t)(r0 + row) * 512 + c8];
  }
  __syncthreads();

  {
    const int ct1 = wave & 1, kh = wave >> 1;
    f32x4 acc = {0.f, 0.f, 0.f, 0.f};
#pragma unroll
    for (int ks = 0; ks < 8; ++ks) {
      const int K = kh * 256 + ks * 32 + g * 8;
      const bf16x8 aw = *(const bf16x8*)&pw1bf[(size_t)(ct1 * 16 + lrow) * 512 + K];
      const bf16x8 bf = *(const bf16x8*)&yb[lrow][K];
      acc = __builtin_amdgcn_mfma_f32_16x16x32_bf16(aw, bf, acc, 0, 0, 0);
    }
#pragma unroll
    for (int j = 0; j < 4; ++j)
      tp_part[kh][ct1 * 16 + g * 4 + j][lrow] = acc[j];
  }
  __syncthreads();

  union { u16 a[8]; bf16x8 v; } bq;
#pragma unroll
  for (int i = 0; i < 8; ++i) {
    const int k = g * 8 + i;
    bq.a[i] = f2bf(tp_part[0][k][lrow] + tp_part[1][k][lrow]);
  }

#pragma unroll
  for (int t = 0; t < 4; ++t) {
    const int ct = chalf * 16 + wave * 4 + t;
    const bf16x8 aw = *(const bf16x8*)&pw2bf[(size_t)(ct * 16 + lrow) * 32 + g * 8];
    f32x4 acc = {0.f, 0.f, 0.f, 0.f};
    acc = __builtin_amdgcn_mfma_f32_16x16x32_bf16(aw, bq.v, acc, 0, 0, 0);
    float4 res;
    res.x = acc[0]; res.y = acc[1]; res.z = acc[2]; res.w = acc[3];
    *(float4*)&out[(size_t)(r0 + lrow) * 512 + ct * 16 + g * 4] = res;
  }
}

extern "C" void kernel_launch(void* const* d_in, const int* in_sizes, int n_in,
                              void* d_out, int out_size, void* d_ws, size_t ws_size,
                              hipStream_t stream) {
  const float* x     = (const float*)d_in[0];
  const float* q_w1  = (const float*)d_in[1];
  const float* q_w2  = (const float*)d_in[2];
  const float* kv_w1 = (const float*)d_in[3];
  const float* kv_w2 = (const float*)d_in[4];
  const float* dw_w  = (const float*)d_in[5];
  const float* dw_b  = (const float*)d_in[6];
  const float* pw_w  = (const float*)d_in[7];
  const float* pw_b  = (const float*)d_in[8];
  const float* p_w1  = (const float*)d_in[9];
  const float* p_w2  = (const float*)d_in[10];
  float* out = (float*)d_out;

  char* ws = (char*)d_ws;
  float* dsp   = (float*)ws;                      // 2*8*4096 f32 (256KB)
  float* bias2 = (float*)(ws + 262144);           // 1024 f32 (4KB)
  u16*   pwbf  = (u16*)(ws + 262144 + 4096);      // 512*512 u16 (512KB)
  u16*   pw1bf = pwbf + 262144;                   // 16384 u16 (32KB)
  u16*   pw2bf = pw1bf + 16384;                   // 16384 u16 (32KB)
  u16*   t_bf  = pw2bf + 16384;                   // 4096*96 u16 (768KB)
  u16*   qbw   = t_bf + (size_t)NFULL * 96;       // 2M u16 (4MB)
  u16*   kbw   = qbw + (size_t)HEADS * NFULL * DDIM;  // 2M u16 (4MB)
  float* vh    = (float*)(kbw + (size_t)HEADS * NFULL * DDIM);  // 2M f32 (8MB)
  u16*   wv16  = (u16*)(vh + (size_t)HEADS * NFULL * DDIM);     // 2M u16 (4MB)
  u16*   y16   = qbw;  // alias (qb dead after k_attn)

  k_pre<<<202, 256, 0, stream>>>(x, q_w1, kv_w1, t_bf, pw_w, dw_w, dw_b, pw_b,
                                 p_w1, p_w2, bias2, pwbf, pw1bf, pw2bf);
  k_proj2<<<(NFULL / 64) * 12, 256, 0, stream>>>(t_bf, q_w2, kv_w2, qbw, kbw, vh);
  k_attn<<<2 * HEADS * (NFULL / 128), 256, 0, stream>>>(qbw, kbw, vh, wv16, dsp);
  k_dyn<<<(NFULL / 64) * 8, 256, 0, stream>>>(wv16, x, pwbf, bias2, dsp, y16);
  k_pout<<<(NFULL / 16) * 2, 256, 0, stream>>>(y16, pw1bf, pw2bf, out);
}

// Round 17
// 75.236 us; speedup vs baseline: 2.1440x; 1.1071x over previous
//
#include <hip/hip_runtime.h>

#define NFULL 4096
#define CDIM  512
#define HEADS 8
#define DDIM  64

typedef unsigned short u16;
typedef short bf16x8 __attribute__((ext_vector_type(8)));
typedef float f32x4 __attribute__((ext_vector_type(4)));

#if __has_builtin(__builtin_amdgcn_exp2f)
__device__ __forceinline__ float exp2_hw(float x) { return __builtin_amdgcn_exp2f(x); }
#else
__device__ __forceinline__ float exp2_hw(float x) {
  float r;
  asm volatile("v_exp_f32 %0, %1\n\ts_nop 1" : "=v"(r) : "v"(x));
  return r;
}
#endif
#define EXP2(x) exp2_hw(x)

// q pre-scaled by SCALE * log2(e) so exp(s) == exp2(s').
#define QSCALE 11.541560327111707f  // 8 * 1.4426950408889634

__device__ __forceinline__ float dot4(float4 a, float4 b) {
  return a.x * b.x + a.y * b.y + a.z * b.z + a.w * b.w;
}

__device__ __forceinline__ u16 f2bf(float x) {  // RNE f32 -> bf16 bits
  union { float f; unsigned u; } v; v.f = x;
  unsigned r = v.u + 0x7fffu + ((v.u >> 16) & 1u);
  return (u16)(r >> 16);
}

__device__ __forceinline__ float bf2f(u16 b) {
  union { unsigned u; float f; } v; v.u = ((unsigned)b) << 16;
  return v.f;
}

// K1: blocks 0..127: t_bf[32 rows][96] = bf16(x @ [q_w1;kv_w1]^T), MFMA.
// 128..129: bias2 = dw_b@pw_w^T + pw_b.
// 130..193: W_c[r][k] = bf16( dww[k] * sum_c pw1[r][c]*pww[c][k] )  (r=b>>1, khalf=b&1)
// 194..197: pw1bf = bf16(p_w1). 198..201: pw2bf = bf16(p_w2).
__global__ __launch_bounds__(256) void k_pre(const float* __restrict__ x,
                                             const float* __restrict__ qw1,
                                             const float* __restrict__ kvw1,
                                             u16* __restrict__ t_bf,
                                             const float* __restrict__ pww,
                                             const float* __restrict__ dww,
                                             const float* __restrict__ dwb,
                                             const float* __restrict__ pwb,
                                             const float* __restrict__ pw1,
                                             const float* __restrict__ pw2,
                                             float* __restrict__ bias2,
                                             u16* __restrict__ wcbf,
                                             u16* __restrict__ pw1bf,
                                             u16* __restrict__ pw2bf) {
  __shared__ __align__(16) u16 Xs[32][72];
  __shared__ __align__(16) u16 Ws[96][72];
  const int tid = threadIdx.x;

  if (blockIdx.x >= 128) {  // prep work
    const int b = blockIdx.x - 128;
    if (b < 2) {
      const int c = b * 256 + tid;
      float acc = 0.f;
      for (int e = 0; e < 512; e += 4)
        acc += dot4(*(const float4*)&pww[(size_t)c * 512 + e], *(const float4*)&dwb[e]);
      bias2[c] = acc + pwb[c];
    } else if (b < 66) {  // W_c: composed low-rank x pointwise weight
      const int b2 = b - 2;
      const int r = b2 >> 1;
      const int k = (b2 & 1) * 256 + tid;
      float acc = 0.f;
      for (int c = 0; c < 512; c += 4) {
        const float4 p = *(const float4*)&pw1[(size_t)r * 512 + c];
        acc += p.x * pww[(size_t)(c + 0) * 512 + k];
        acc += p.y * pww[(size_t)(c + 1) * 512 + k];
        acc += p.z * pww[(size_t)(c + 2) * 512 + k];
        acc += p.w * pww[(size_t)(c + 3) * 512 + k];
      }
      wcbf[(size_t)r * 512 + k] = f2bf(acc * dww[k]);
    } else {
      const float* src;
      u16* dst;
      int base;
      if (b < 70) { base = (b - 66) * 4096 + tid * 16; src = pw1; dst = pw1bf; }
      else        { base = (b - 70) * 4096 + tid * 16; src = pw2; dst = pw2bf; }
      u16 o[16];
#pragma unroll
      for (int q = 0; q < 4; ++q) {
        const float4 w = *(const float4*)&src[base + q * 4];
        o[q * 4 + 0] = f2bf(w.x); o[q * 4 + 1] = f2bf(w.y);
        o[q * 4 + 2] = f2bf(w.z); o[q * 4 + 3] = f2bf(w.w);
      }
      *(uint4*)&dst[base] = *(const uint4*)&o[0];
      *(uint4*)&dst[base + 8] = *(const uint4*)&o[8];
    }
    return;
  }

  const int r0 = blockIdx.x * 32;
  const int wave = tid >> 6, lane = tid & 63;
  const int lrow = lane & 15, g = lane >> 4;
  const int rs = wave >> 1, ws2 = wave & 1;

  f32x4 acc[3];
#pragma unroll
  for (int sub = 0; sub < 3; ++sub) acc[sub] = (f32x4){0.f, 0.f, 0.f, 0.f};

  for (int k0 = 0; k0 < 512; k0 += 64) {
    __syncthreads();
    {
      const int row = tid >> 3, c16 = (tid & 7) * 8;
      const float* __restrict__ src = x + (size_t)(r0 + row) * 512 + k0 + c16;
      const float4 v0 = *(const float4*)(src);
      const float4 v1 = *(const float4*)(src + 4);
      u16 tmp[8] = {f2bf(v0.x), f2bf(v0.y), f2bf(v0.z), f2bf(v0.w),
                    f2bf(v1.x), f2bf(v1.y), f2bf(v1.z), f2bf(v1.w)};
      *(uint4*)&Xs[row][c16] = *(const uint4*)&tmp[0];
    }
    for (int u = tid; u < 768; u += 256) {
      const int c = u >> 3, c16 = (u & 7) * 8;
      const float* __restrict__ src =
          (c < 32 ? qw1 + (size_t)c * 512 : kvw1 + (size_t)(c - 32) * 512) + k0 + c16;
      const float4 v0 = *(const float4*)(src);
      const float4 v1 = *(const float4*)(src + 4);
      u16 tmp[8] = {f2bf(v0.x), f2bf(v0.y), f2bf(v0.z), f2bf(v0.w),
                    f2bf(v1.x), f2bf(v1.y), f2bf(v1.z), f2bf(v1.w)};
      *(uint4*)&Ws[c][c16] = *(const uint4*)&tmp[0];
    }
    __syncthreads();
    const bf16x8 a0 = *(const bf16x8*)&Xs[rs * 16 + lrow][g * 8];
    const bf16x8 a1 = *(const bf16x8*)&Xs[rs * 16 + lrow][32 + g * 8];
#pragma unroll
    for (int sub = 0; sub < 3; ++sub) {
      const int c = (ws2 * 3 + sub) * 16 + lrow;
      const bf16x8 b0 = *(const bf16x8*)&Ws[c][g * 8];
      const bf16x8 b1 = *(const bf16x8*)&Ws[c][32 + g * 8];
      acc[sub] = __builtin_amdgcn_mfma_f32_16x16x32_bf16(b0, a0, acc[sub], 0, 0, 0);
      acc[sub] = __builtin_amdgcn_mfma_f32_16x16x32_bf16(b1, a1, acc[sub], 0, 0, 0);
    }
  }
  const int n = r0 + rs * 16 + lrow;
#pragma unroll
  for (int sub = 0; sub < 3; ++sub) {
    u16 o4[4] = {f2bf(acc[sub][0]), f2bf(acc[sub][1]),
                 f2bf(acc[sub][2]), f2bf(acc[sub][3])};
    *(uint2*)&t_bf[(size_t)n * 96 + (ws2 * 3 + sub) * 16 + g * 4] = *(const uint2*)o4;
  }
}

// K2: q/k/v projections (blocks 0..767). Block 768: bias_c = bias2 @ p_w1^T.
__global__ __launch_bounds__(256) void k_proj2(const u16* __restrict__ t_bf,
                                               const float* __restrict__ qw2,
                                               const float* __restrict__ kvw2,
                                               const float* __restrict__ pw1,
                                               const float* __restrict__ bias2,
                                               u16* __restrict__ qb,
                                               u16* __restrict__ kb,
                                               float* __restrict__ vh,
                                               float* __restrict__ bias_c) {
  __shared__ __align__(16) u16 Ts[64][72];
  __shared__ __align__(16) u16 Wsh[128][72];
  __shared__ float red[8][32];
  const int tid = threadIdx.x;

  if (blockIdx.x >= 768) {  // bias_c[32]
    const int r = tid & 31, part = tid >> 5;  // 8 parts x 64 c
    float acc = 0.f;
    for (int c = part * 64; c < part * 64 + 64; ++c)
      acc += bias2[c] * pw1[(size_t)r * 512 + c];
    red[part][r] = acc;
    __syncthreads();
    if (tid < 32) {
      float s = 0.f;
#pragma unroll
      for (int p = 0; p < 8; ++p) s += red[p][tid];
      bias_c[tid] = s;
    }
    return;
  }

  const int cb = blockIdx.x % 12;
  const int r0 = (blockIdx.x / 12) * 64;
  const int wave = tid >> 6, lane = tid & 63;
  const int lrow = lane & 15, g = lane >> 4;
  const bool isq = cb < 4;
  const int c0 = isq ? cb * 128 : 512 + (cb - 4) * 128;

  for (int u = tid; u < 512; u += 256) {
    const int row = u >> 3, ch = (u & 7) * 8;
    uint4 v = {0u, 0u, 0u, 0u};
    if (isq) {
      if (ch < 32) v = *(const uint4*)&t_bf[(size_t)(r0 + row) * 96 + ch];
    } else {
      v = *(const uint4*)&t_bf[(size_t)(r0 + row) * 96 + 32 + ch];
    }
    *(uint4*)&Ts[row][ch] = v;
  }
  if (isq) {
    for (int u = tid; u < 1024; u += 256) {
      const int col = u >> 3, cf = (u & 7) * 4;
      const float4 v = *(const float4*)&qw2[(size_t)(c0 + col) * 32 + cf];
      u16 tmp[4] = {f2bf(v.x), f2bf(v.y), f2bf(v.z), f2bf(v.w)};
      *(uint2*)&Wsh[col][cf] = *(const uint2*)&tmp[0];
    }
  } else {
    for (int u = tid; u < 2048; u += 256) {
      const int col = u >> 4, cf = (u & 15) * 4;
      const float4 v = *(const float4*)&kvw2[(size_t)(c0 - 512 + col) * 64 + cf];
      u16 tmp[4] = {f2bf(v.x), f2bf(v.y), f2bf(v.z), f2bf(v.w)};
      *(uint2*)&Wsh[col][cf] = *(const uint2*)&tmp[0];
    }
  }
  __syncthreads();

  const int n = r0 + wave * 16 + lrow;
  if (isq) {
    const bf16x8 aq = *(const bf16x8*)&Ts[wave * 16 + lrow][g * 8];
#pragma unroll
    for (int sub = 0; sub < 8; ++sub) {
      const bf16x8 b0 = *(const bf16x8*)&Wsh[sub * 16 + lrow][g * 8];
      f32x4 acc = {0.f, 0.f, 0.f, 0.f};
      acc = __builtin_amdgcn_mfma_f32_16x16x32_bf16(b0, aq, acc, 0, 0, 0);
      const int colg0 = c0 + sub * 16 + g * 4;
      const int hh = colg0 >> 6, d0 = colg0 & 63;
      u16 o4[4] = {f2bf(acc[0] * QSCALE), f2bf(acc[1] * QSCALE),
                   f2bf(acc[2] * QSCALE), f2bf(acc[3] * QSCALE)};
      *(uint2*)&qb[((size_t)hh * NFULL + n) * 64 + d0] = *(const uint2*)o4;
    }
  } else {
    const bf16x8 a0 = *(const bf16x8*)&Ts[wave * 16 + lrow][g * 8];
    const bf16x8 a1 = *(const bf16x8*)&Ts[wave * 16 + lrow][32 + g * 8];
#pragma unroll
    for (int sub = 0; sub < 8; ++sub) {
      const bf16x8 b0 = *(const bf16x8*)&Wsh[sub * 16 + lrow][g * 8];
      const bf16x8 b1 = *(const bf16x8*)&Wsh[sub * 16 + lrow][32 + g * 8];
      f32x4 acc = {0.f, 0.f, 0.f, 0.f};
      acc = __builtin_amdgcn_mfma_f32_16x16x32_bf16(b0, a0, acc, 0, 0, 0);
      acc = __builtin_amdgcn_mfma_f32_16x16x32_bf16(b1, a1, acc, 0, 0, 0);
      const int colg0 = c0 + sub * 16 + g * 4;
      if (colg0 < 1024) {
        const int c2 = colg0 - 512;
        const int hh = c2 >> 6, d0 = c2 & 63;
        u16 o4[4] = {f2bf(acc[0]), f2bf(acc[1]), f2bf(acc[2]), f2bf(acc[3])};
        *(uint2*)&kb[((size_t)hh * NFULL + n) * 64 + d0] = *(const uint2*)o4;
      } else {
        const int c2 = colg0 - 1024;
        const int hh = c2 >> 6, d0 = c2 & 63;
        float4 o4;
        o4.x = acc[0]; o4.y = acc[1]; o4.z = acc[2]; o4.w = acc[3];
        *(float4*)&vh[((size_t)hh * NFULL + n) * 64 + d0] = o4;
      }
    }
  }
}

// K3: attention (frozen R16 structure). Block (h, qt, s): 128 queries, keys
// [s*2048,+2048) in 32 tiles; wave-private global_load_lds staging, 4-deep
// circular swizzled LDS buffer, counted vmcnt, no main-loop barriers.
__global__ __launch_bounds__(256, 2) void k_attn(const u16* __restrict__ qb,
                                                 const u16* __restrict__ kb,
                                                 const float* __restrict__ vh,
                                                 u16* __restrict__ wv16,
                                                 float* __restrict__ dsp) {
  __shared__ __align__(16) u16 KB[4][64][64];
  __shared__ float P_lds[8][16][17];
  __shared__ float Ds[4][8][16];

  const int h = blockIdx.x & 7;
  const int qt = (blockIdx.x >> 3) & 31;
  const int s = blockIdx.x >> 8;
  const int q0 = qt * 128;
  const int tid = threadIdx.x;
  const int wave = tid >> 6, lane = tid & 63;
  const int lrow = lane & 15, g = lane >> 4;

  const u16* __restrict__ Qg = qb + ((size_t)h * NFULL + q0) * 64;
  const u16* __restrict__ Kg = kb + ((size_t)h * NFULL + (size_t)s * 2048) * 64;

  bf16x8 qf[8][2];
#pragma unroll
  for (int j = 0; j < 8; ++j) {
    qf[j][0] = *(const bf16x8*)&Qg[(j * 16 + lrow) * 64 + g * 8];
    qf[j][1] = *(const bf16x8*)&Qg[(j * 16 + lrow) * 64 + 32 + g * 8];
  }

  const int srow8 = lane >> 3;
  const int scol = ((lane & 7) ^ srow8) << 3;

#define STAGE(T, B)                                                           \
  do {                                                                        \
    const u16* tb_ = Kg + (size_t)(T) * 64 * 64;                              \
    {                                                                         \
      const u16* src_ = tb_ + (wave * 16 + srow8) * 64 + scol;                \
      u16* dst_ = &KB[(B)][wave * 16][0];                                     \
      __builtin_amdgcn_global_load_lds(                                       \
          (const __attribute__((address_space(1))) unsigned*)src_,            \
          (__attribute__((address_space(3))) unsigned*)dst_, 16, 0, 0);       \
    }                                                                         \
    {                                                                         \
      const u16* src_ = tb_ + (wave * 16 + 8 + srow8) * 64 + scol;            \
      u16* dst_ = &KB[(B)][wave * 16][0] + 512;                               \
      __builtin_amdgcn_global_load_lds(                                       \
          (const __attribute__((address_space(1))) unsigned*)src_,            \
          (__attribute__((address_space(3))) unsigned*)dst_, 16, 0, 0);       \
    }                                                                         \
  } while (0)

  const int rsw = wave * 16 + lrow;
  const int x0 = (g ^ (lrow & 7)) * 8;
  const int x1 = ((g + 4) ^ (lrow & 7)) * 8;

  float dsum[8];
#pragma unroll
  for (int j = 0; j < 8; ++j) dsum[j] = 0.f;
  const bool dg = (s == (qt >> 4));
  const int ql = qt & 15;

  auto tile = [&](int t, int b) {
    const bf16x8 kf0 = *(const bf16x8*)&KB[b][rsw][x0];
    const bf16x8 kf1 = *(const bf16x8*)&KB[b][rsw][x1];
#pragma unroll
    for (int hs = 0; hs < 2; ++hs) {
      f32x4 a[4];
      __builtin_amdgcn_s_setprio(1);
#pragma unroll
      for (int f = 0; f < 4; ++f) {
        f32x4 t4 = {0.f, 0.f, 0.f, 0.f};
        t4 = __builtin_amdgcn_mfma_f32_16x16x32_bf16(kf0, qf[hs * 4 + f][0], t4, 0, 0, 0);
        t4 = __builtin_amdgcn_mfma_f32_16x16x32_bf16(kf1, qf[hs * 4 + f][1], t4, 0, 0, 0);
        a[f] = t4;
      }
      __builtin_amdgcn_s_setprio(0);
      const bool isd = dg && (t == ql * 2 + hs);
#pragma unroll
      for (int f = 0; f < 4; ++f) {
        const float e0 = EXP2(a[f][0]);
        const float e1 = EXP2(a[f][1]);
        const float e2 = EXP2(a[f][2]);
        const float e3 = EXP2(a[f][3]);
        dsum[hs * 4 + f] += (e0 + e1) + (e2 + e3);
        if (isd && f == wave) {
          const int rr = g * 4;
          const int J = hs * 4 + wave;
          P_lds[J][rr + 0][lrow] = (rr + 0 <= lrow) ? e0 : 0.f;
          P_lds[J][rr + 1][lrow] = (rr + 1 <= lrow) ? e1 : 0.f;
          P_lds[J][rr + 2][lrow] = (rr + 2 <= lrow) ? e2 : 0.f;
          P_lds[J][rr + 3][lrow] = (rr + 3 <= lrow) ? e3 : 0.f;
        }
      }
    }
  };

  STAGE(0, 0); STAGE(1, 1); STAGE(2, 2);

  for (int t = 0; t < 28; t += 2) {
    STAGE(t + 3, (t + 3) & 3);
    asm volatile("s_waitcnt vmcnt(6)" ::: "memory");
    tile(t, t & 3);
    STAGE(t + 4, (t + 4) & 3);
    asm volatile("s_waitcnt vmcnt(6)" ::: "memory");
    tile(t + 1, (t + 1) & 3);
  }
  STAGE(31, 3);
  asm volatile("s_waitcnt vmcnt(6)" ::: "memory");
  tile(28, 0);
  asm volatile("s_waitcnt vmcnt(4)" ::: "memory");
  tile(29, 1);
  asm volatile("s_waitcnt vmcnt(2)" ::: "memory");
  tile(30, 2);
  asm volatile("s_waitcnt vmcnt(0)" ::: "memory");
  tile(31, 3);
#undef STAGE

#pragma unroll
  for (int j = 0; j < 8; ++j) {
    dsum[j] += __shfl_xor(dsum[j], 16);
    dsum[j] += __shfl_xor(dsum[j], 32);
  }
  if (g == 0) {
#pragma unroll
    for (int j = 0; j < 8; ++j) Ds[wave][j][lrow] = dsum[j];
  }
  __syncthreads();

  if (tid < 128) {
    const int J2 = tid >> 4, r = tid & 15;
    const float den = Ds[0][J2][r] + Ds[1][J2][r] + Ds[2][J2][r] + Ds[3][J2][r];
    dsp[((size_t)s * HEADS + h) * NFULL + q0 + J2 * 16 + r] = den;
  }

  if (dg) {
#pragma unroll
    for (int m = 0; m < 2; ++m) {
      const int J = m * 4 + wave;
      const float* __restrict__ V =
          vh + ((size_t)h * NFULL + q0 + J * 16) * 64 + g * 16;
      float o[16];
#pragma unroll
      for (int dd = 0; dd < 16; ++dd) o[dd] = 0.f;
#pragma unroll
      for (int k = 0; k < 16; ++k) {
        const float p = P_lds[J][k][lrow];
        const float4 v0 = *(const float4*)&V[k * 64 + 0];
        const float4 v1 = *(const float4*)&V[k * 64 + 4];
        const float4 v2 = *(const float4*)&V[k * 64 + 8];
        const float4 v3 = *(const float4*)&V[k * 64 + 12];
        o[0] += p * v0.x;  o[1] += p * v0.y;  o[2] += p * v0.z;  o[3] += p * v0.w;
        o[4] += p * v1.x;  o[5] += p * v1.y;  o[6] += p * v1.z;  o[7] += p * v1.w;
        o[8] += p * v2.x;  o[9] += p * v2.y;  o[10] += p * v2.z; o[11] += p * v2.w;
        o[12] += p * v3.x; o[13] += p * v3.y; o[14] += p * v3.z; o[15] += p * v3.w;
      }
      u16 ob[16];
#pragma unroll
      for (int dd = 0; dd < 16; ++dd) ob[dd] = f2bf(o[dd]);
      u16* __restrict__ op =
          wv16 + (size_t)(q0 + J * 16 + lrow) * CDIM + h * 64 + g * 16;
      *(uint4*)&op[0] = *(const uint4*)&ob[0];
      *(uint4*)&op[8] = *(const uint4*)&ob[8];
    }
  }
}

// K4 (fused, replaces k_dyn+k_pout): per 16-row block,
// tp[16][32] = norm(wv) @ W_c^T + x @ p_w1^T + bias_c ;  out = tp @ p_w2^T.
// Grid 256, 4 waves: wave 0/1 = wv-term K halves, wave 2/3 = x-term K halves.
__global__ __launch_bounds__(256) void k_out(const u16* __restrict__ wv16,
                                             const float* __restrict__ x,
                                             const float* __restrict__ dsp,
                                             const u16* __restrict__ wcbf,
                                             const u16* __restrict__ pw1bf,
                                             const u16* __restrict__ pw2bf,
                                             const float* __restrict__ bias_c,
                                             float* __restrict__ out) {
  __shared__ __align__(16) u16 wvb[16][520];
  __shared__ __align__(16) u16 xb[16][520];
  __shared__ float tp_part[4][32][17];
  __shared__ float invs[16][8];
  const int r0 = blockIdx.x * 16;
  const int tid = threadIdx.x;
  const int wave = tid >> 6, lane = tid & 63;
  const int lrow = lane & 15, g = lane >> 4;

  if (tid < 128) {  // per-(row, head) softmax inverse denominators
    const int n = tid >> 3, hh = tid & 7;
    const size_t base = (size_t)hh * NFULL + r0 + n;
    invs[n][hh] = 1.0f / (dsp[base] + dsp[(size_t)8 * NFULL + base]);
  }
  __syncthreads();

  for (int rep = 0; rep < 4; ++rep) {  // stage 16 rows: norm(wv) and x as bf16
    const int idx = rep * 256 + tid;   // 1024 chunks of 8
    const int row = idx >> 6, c8 = (idx & 63) * 8;
    const float sc = invs[row][c8 >> 6];
    const uint4 wv8 = *(const uint4*)&wv16[(size_t)(r0 + row) * 512 + c8];
    const u16* pw = (const u16*)&wv8;
    u16 t8[8];
#pragma unroll
    for (int i = 0; i < 8; ++i) t8[i] = f2bf(bf2f(pw[i]) * sc);
    *(uint4*)&wvb[row][c8] = *(const uint4*)&t8[0];
    const float4 x0 = *(const float4*)&x[(size_t)(r0 + row) * 512 + c8];
    const float4 x1 = *(const float4*)&x[(size_t)(r0 + row) * 512 + c8 + 4];
    u16 u8[8] = {f2bf(x0.x), f2bf(x0.y), f2bf(x0.z), f2bf(x0.w),
                 f2bf(x1.x), f2bf(x1.y), f2bf(x1.z), f2bf(x1.w)};
    *(uint4*)&xb[row][c8] = *(const uint4*)&u8[0];
  }
  __syncthreads();

  {  // phase 1: tp partials
    const bool isx = (wave & 2) != 0;
    const int kh = wave & 1;
    const u16* __restrict__ Wsrc = isx ? pw1bf : wcbf;
#pragma unroll
    for (int rt = 0; rt < 2; ++rt) {
      f32x4 acc = {0.f, 0.f, 0.f, 0.f};
#pragma unroll
      for (int ks = 0; ks < 8; ++ks) {
        const int K = kh * 256 + ks * 32 + g * 8;
        const bf16x8 aw = *(const bf16x8*)&Wsrc[(size_t)(rt * 16 + lrow) * 512 + K];
        const bf16x8 bf = isx ? *(const bf16x8*)&xb[lrow][K]
                              : *(const bf16x8*)&wvb[lrow][K];
        acc = __builtin_amdgcn_mfma_f32_16x16x32_bf16(aw, bf, acc, 0, 0, 0);
      }
#pragma unroll
      for (int j = 0; j < 4; ++j)
        tp_part[wave][rt * 16 + g * 4 + j][lrow] = acc[j];
    }
  }
  __syncthreads();

  union { u16 a[8]; bf16x8 v; } bq;  // tp B-frag: lane holds tp[n=lrow][k=g*8+i]
#pragma unroll
  for (int i = 0; i < 8; ++i) {
    const int k = g * 8 + i;
    bq.a[i] = f2bf(tp_part[0][k][lrow] + tp_part[1][k][lrow] +
                   tp_part[2][k][lrow] + tp_part[3][k][lrow] + bias_c[k]);
  }

#pragma unroll
  for (int t = 0; t < 8; ++t) {  // phase 2: out = tp @ p_w2^T
    const int ct = wave * 8 + t;
    const bf16x8 aw = *(const bf16x8*)&pw2bf[(size_t)(ct * 16 + lrow) * 32 + g * 8];
    f32x4 acc = {0.f, 0.f, 0.f, 0.f};
    acc = __builtin_amdgcn_mfma_f32_16x16x32_bf16(aw, bq.v, acc, 0, 0, 0);
    float4 res;
    res.x = acc[0]; res.y = acc[1]; res.z = acc[2]; res.w = acc[3];
    *(float4*)&out[(size_t)(r0 + lrow) * 512 + ct * 16 + g * 4] = res;
  }
}

extern "C" void kernel_launch(void* const* d_in, const int* in_sizes, int n_in,
                              void* d_out, int out_size, void* d_ws, size_t ws_size,
                              hipStream_t stream) {
  const float* x     = (const float*)d_in[0];
  const float* q_w1  = (const float*)d_in[1];
  const float* q_w2  = (const float*)d_in[2];
  const float* kv_w1 = (const float*)d_in[3];
  const float* kv_w2 = (const float*)d_in[4];
  const float* dw_w  = (const float*)d_in[5];
  const float* dw_b  = (const float*)d_in[6];
  const float* pw_w  = (const float*)d_in[7];
  const float* pw_b  = (const float*)d_in[8];
  const float* p_w1  = (const float*)d_in[9];
  const float* p_w2  = (const float*)d_in[10];
  float* out = (float*)d_out;

  char* ws = (char*)d_ws;
  float* dsp    = (float*)ws;                        // 2*8*4096 f32 (256KB)
  float* bias2  = (float*)(ws + 262144);             // 512 f32
  float* bias_c = (float*)(ws + 262144 + 4096);      // 32 f32
  u16*   wcbf   = (u16*)(ws + 262144 + 8192);        // 32*512 u16 (32KB)
  u16*   pw1bf  = wcbf + 16384;                      // 32KB
  u16*   pw2bf  = pw1bf + 16384;                     // 32KB
  u16*   t_bf   = pw2bf + 16384;                     // 4096*96 u16 (768KB)
  u16*   qbw    = t_bf + (size_t)NFULL * 96;         // 2M u16 (4MB)
  u16*   kbw    = qbw + (size_t)HEADS * NFULL * DDIM;  // 2M u16 (4MB)
  float* vh     = (float*)(kbw + (size_t)HEADS * NFULL * DDIM);  // 2M f32 (8MB)
  u16*   wv16   = (u16*)(vh + (size_t)HEADS * NFULL * DDIM);     // 2M u16 (4MB)

  k_pre<<<202, 256, 0, stream>>>(x, q_w1, kv_w1, t_bf, pw_w, dw_w, dw_b, pw_b,
                                 p_w1, p_w2, bias2, wcbf, pw1bf, pw2bf);
  k_proj2<<<769, 256, 0, stream>>>(t_bf, q_w2, kv_w2, p_w1, bias2, qbw, kbw, vh,
                                   bias_c);
  k_attn<<<2 * HEADS * (NFULL / 128), 256, 0, stream>>>(qbw, kbw, vh, wv16, dsp);
  k_out<<<NFULL / 16, 256, 0, stream>>>(wv16, x, dsp, wcbf, pw1bf, pw2bf, bias_c,
                                        out);
}